// Round 1
// baseline (1331.856 us; speedup 1.0000x reference)
//
#include <hip/hip_runtime.h>
#include <hip/hip_bf16.h>
#include <math.h>

#define EMBED_DIM 1024
#define NUM_HEADS 16
#define HEAD_DIM  64
#define B_SZ      2
#define T_SZ      2048
#define BT        (B_SZ * T_SZ)      // 4096
#define SOFTMAX_SCALE 0.125f         // 1/sqrt(64)

// ---------------------------------------------------------------------------
// Kernel 1: fused QKV projection.
// C[m, (type,h,e)] = hs[m,:] @ W_type[h,:,e] + b_type[h,e]
// Output layout: [B, H, T, hd] so attention reads contiguous (b,h) slabs.
// grid = (BT/64, 48) where blockIdx.y = type*16 + h; block = 256 (16x16),
// each thread owns a 4x4 register tile of the 64x64 output tile.
// ---------------------------------------------------------------------------
__global__ __launch_bounds__(256) void qkv_proj_kernel(
    const float* __restrict__ hs,
    const float* __restrict__ Wq, const float* __restrict__ bq,
    const float* __restrict__ Wk, const float* __restrict__ bk,
    const float* __restrict__ Wv, const float* __restrict__ bv,
    float* __restrict__ Qout, float* __restrict__ Kout, float* __restrict__ Vout)
{
    const int m0   = blockIdx.x * 64;
    const int type = blockIdx.y >> 4;
    const int h    = blockIdx.y & 15;

    const float* W;  const float* bias;  float* out;
    if (type == 0)      { W = Wq; bias = bq; out = Qout; }
    else if (type == 1) { W = Wk; bias = bk; out = Kout; }
    else                { W = Wv; bias = bv; out = Vout; }
    W    += (size_t)h * EMBED_DIM * HEAD_DIM;   // [D, hd] for this head
    bias += (size_t)h * HEAD_DIM;

    __shared__ float As[64][17];   // +1 pad breaks stride-16 conflicts
    __shared__ float Ws[16][64];

    const int tid = threadIdx.x;
    const int ty  = tid >> 4, tx = tid & 15;

    float acc[4][4] = {};

    for (int k0 = 0; k0 < EMBED_DIM; k0 += 16) {
        {   // A tile 64x16: thread -> row tid>>2, cols (tid&3)*4..+3
            const int r = tid >> 2, c = (tid & 3) * 4;
            const float4 a = *(const float4*)&hs[(size_t)(m0 + r) * EMBED_DIM + k0 + c];
            As[r][c + 0] = a.x; As[r][c + 1] = a.y; As[r][c + 2] = a.z; As[r][c + 3] = a.w;
        }
        {   // W tile 16x64 (contiguous rows of 64 -> coalesced float4)
            const int kk = tid >> 4, c = (tid & 15) * 4;
            const float4 w = *(const float4*)&W[(size_t)(k0 + kk) * HEAD_DIM + c];
            *(float4*)&Ws[kk][c] = w;
        }
        __syncthreads();
        #pragma unroll
        for (int kk = 0; kk < 16; ++kk) {
            float a[4], w[4];
            #pragma unroll
            for (int i = 0; i < 4; ++i) a[i] = As[ty * 4 + i][kk];
            #pragma unroll
            for (int j = 0; j < 4; ++j) w[j] = Ws[kk][tx * 4 + j];
            #pragma unroll
            for (int i = 0; i < 4; ++i)
                #pragma unroll
                for (int j = 0; j < 4; ++j) acc[i][j] += a[i] * w[j];
        }
        __syncthreads();
    }

    float bj[4];
    #pragma unroll
    for (int j = 0; j < 4; ++j) bj[j] = bias[tx * 4 + j];

    const int b      = m0 >> 11;        // m0 / 2048 (tile never straddles b)
    const int t_base = m0 & 2047;
    float* obase = out + ((size_t)b * NUM_HEADS + h) * T_SZ * HEAD_DIM;
    #pragma unroll
    for (int i = 0; i < 4; ++i) {
        float4 v;
        v.x = acc[i][0] + bj[0]; v.y = acc[i][1] + bj[1];
        v.z = acc[i][2] + bj[2]; v.w = acc[i][3] + bj[3];
        *(float4*)&obase[(size_t)(t_base + ty * 4 + i) * HEAD_DIM + tx * 4] = v;
    }
}

// ---------------------------------------------------------------------------
// Kernel 2: flash-style attention per (b,h). grid = (T/64, H, B), block 256.
// 64-query x 64-key tiles, online softmax (m,l per row), P staged via LDS for
// the PV GEMM. Epilogue: O /= l, write [B,H,T,hd], block-reduce sum of row L2
// norms, one atomicAdd per block into denomsum[h].
// ---------------------------------------------------------------------------
__global__ __launch_bounds__(256) void attn_kernel(
    const float* __restrict__ Qg, const float* __restrict__ Kg,
    const float* __restrict__ Vg, const float* __restrict__ mask,
    float* __restrict__ Og, float* __restrict__ denomsum)
{
    const int q0 = blockIdx.x * 64;
    const int h  = blockIdx.y;
    const int b  = blockIdx.z;
    const size_t bh = ((size_t)b * NUM_HEADS + h) * (size_t)T_SZ * HEAD_DIM;

    __shared__ float Qs[64][65];  // 65: stride-260B -> 2-way (free) on row walks
    __shared__ float Ks[64][65];
    __shared__ float Vs[64][65];
    __shared__ float Ps[64][65];
    __shared__ float red[64][16];
    __shared__ float norms_s[64];

    const int tid = threadIdx.x;
    const int ty  = tid >> 4, tx = tid & 15;

    {   // load Q tile (contiguous 4096 floats)
        const float* src = Qg + bh + (size_t)q0 * HEAD_DIM;
        #pragma unroll
        for (int q = 0; q < 4; ++q) {
            const int f = tid * 16 + q * 4;
            const int r = f >> 6, c = f & 63;
            const float4 v = *(const float4*)&src[f];
            Qs[r][c] = v.x; Qs[r][c + 1] = v.y; Qs[r][c + 2] = v.z; Qs[r][c + 3] = v.w;
        }
    }

    float O[4][4] = {};
    float m_i[4], l_i[4];
    #pragma unroll
    for (int i = 0; i < 4; ++i) { m_i[i] = -3.0e38f; l_i[i] = 0.f; }

    for (int kt = 0; kt < T_SZ / 64; ++kt) {
        const int kv0 = kt * 64;
        {   // load K,V tiles
            const float* ksrc = Kg + bh + (size_t)kv0 * HEAD_DIM;
            const float* vsrc = Vg + bh + (size_t)kv0 * HEAD_DIM;
            #pragma unroll
            for (int q = 0; q < 4; ++q) {
                const int f = tid * 16 + q * 4;
                const int r = f >> 6, c = f & 63;
                const float4 kv = *(const float4*)&ksrc[f];
                Ks[r][c] = kv.x; Ks[r][c + 1] = kv.y; Ks[r][c + 2] = kv.z; Ks[r][c + 3] = kv.w;
                const float4 vv = *(const float4*)&vsrc[f];
                Vs[r][c] = vv.x; Vs[r][c + 1] = vv.y; Vs[r][c + 2] = vv.z; Vs[r][c + 3] = vv.w;
            }
        }
        __syncthreads();   // K/V (and first-iter Q) visible

        // S = Q K^T (4x4 per thread)
        float s[4][4] = {};
        for (int d = 0; d < 64; ++d) {
            float qv[4], kv[4];
            #pragma unroll
            for (int i = 0; i < 4; ++i) qv[i] = Qs[ty * 4 + i][d];
            #pragma unroll
            for (int j = 0; j < 4; ++j) kv[j] = Ks[tx * 4 + j][d];
            #pragma unroll
            for (int i = 0; i < 4; ++i)
                #pragma unroll
                for (int j = 0; j < 4; ++j) s[i][j] += qv[i] * kv[j];
        }
        #pragma unroll
        for (int i = 0; i < 4; ++i) {
            const float* mrow = mask + (size_t)(q0 + ty * 4 + i) * T_SZ + kv0 + tx * 4;
            #pragma unroll
            for (int j = 0; j < 4; ++j) s[i][j] = s[i][j] * SOFTMAX_SCALE + mrow[j];
        }

        // row-max partials across the 16 tx threads
        #pragma unroll
        for (int i = 0; i < 4; ++i)
            red[ty * 4 + i][tx] = fmaxf(fmaxf(s[i][0], s[i][1]), fmaxf(s[i][2], s[i][3]));
        __syncthreads();
        float m_new[4], alpha[4];
        #pragma unroll
        for (int i = 0; i < 4; ++i) {
            float mx = m_i[i];
            for (int x = 0; x < 16; ++x) mx = fmaxf(mx, red[ty * 4 + i][x]);
            m_new[i] = mx;
            alpha[i] = __expf(m_i[i] - mx);
        }
        __syncthreads();   // red about to be reused

        // P = exp(s - m_new), row-sum partials, stage P in LDS
        #pragma unroll
        for (int i = 0; i < 4; ++i) {
            float rs = 0.f;
            #pragma unroll
            for (int j = 0; j < 4; ++j) {
                const float p = __expf(s[i][j] - m_new[i]);
                Ps[ty * 4 + i][tx * 4 + j] = p;
                rs += p;
            }
            red[ty * 4 + i][tx] = rs;
        }
        __syncthreads();
        #pragma unroll
        for (int i = 0; i < 4; ++i) {
            float rs = 0.f;
            for (int x = 0; x < 16; ++x) rs += red[ty * 4 + i][x];
            l_i[i] = l_i[i] * alpha[i] + rs;
            m_i[i] = m_new[i];
            #pragma unroll
            for (int j = 0; j < 4; ++j) O[i][j] *= alpha[i];
        }

        // O += P V
        for (int k = 0; k < 64; ++k) {
            float pv[4], vv[4];
            #pragma unroll
            for (int i = 0; i < 4; ++i) pv[i] = Ps[ty * 4 + i][k];
            #pragma unroll
            for (int j = 0; j < 4; ++j) vv[j] = Vs[k][tx * 4 + j];
            #pragma unroll
            for (int i = 0; i < 4; ++i)
                #pragma unroll
                for (int j = 0; j < 4; ++j) O[i][j] += pv[i] * vv[j];
        }
        __syncthreads();   // before K/V/Ps/red are overwritten
    }

    // epilogue: normalize by l, write O, reduce row L2 norms
    float fin[4][4];
    #pragma unroll
    for (int i = 0; i < 4; ++i) {
        const float inv = 1.f / l_i[i];
        float ss = 0.f;
        #pragma unroll
        for (int j = 0; j < 4; ++j) { fin[i][j] = O[i][j] * inv; ss += fin[i][j] * fin[i][j]; }
        red[ty * 4 + i][tx] = ss;
    }
    {
        float* dst = Og + bh + (size_t)q0 * HEAD_DIM;
        #pragma unroll
        for (int i = 0; i < 4; ++i) {
            float4 v; v.x = fin[i][0]; v.y = fin[i][1]; v.z = fin[i][2]; v.w = fin[i][3];
            *(float4*)&dst[(size_t)(ty * 4 + i) * HEAD_DIM + tx * 4] = v;
        }
    }
    __syncthreads();
    if (tid < 64) {
        float ss = 0.f;
        for (int x = 0; x < 16; ++x) ss += red[tid][x];
        norms_s[tid] = sqrtf(ss);
    }
    __syncthreads();
    if (tid == 0) {
        float tot = 0.f;
        for (int r = 0; r < 64; ++r) tot += norms_s[r];
        atomicAdd(&denomsum[h], tot);
    }
}

// ---------------------------------------------------------------------------
// Kernel 3: output projection + gating + head-sum.
// out[m,n] = sum_h (O[b,h,t,:] . Wo[h,:,n]) * g_h/(denom_h*H) + sum_h g_h*bo[h,n]/H
// Treated as GEMM with K = H*hd = 1024; per-head scale applied on A-load.
// ---------------------------------------------------------------------------
__global__ __launch_bounds__(256) void oproj_kernel(
    const float* __restrict__ Og,
    const float* __restrict__ Wo,      // [H, hd, D]
    const float* __restrict__ bo,      // [H, D]
    const float* __restrict__ gate,    // [H]
    const float* __restrict__ denomsum,
    float* __restrict__ out)           // [BT, D]
{
    const int m0 = blockIdx.x * 64;
    const int n0 = blockIdx.y * 64;

    __shared__ float As[64][17];
    __shared__ float Ws[16][64];
    __shared__ float s_s[NUM_HEADS];
    __shared__ float g_s[NUM_HEADS];

    const int tid = threadIdx.x;
    const int ty  = tid >> 4, tx = tid & 15;

    if (tid < NUM_HEADS) {
        const float g  = fminf(fmaxf(gate[tid], 0.f), 1.f);
        const float dn = fmaxf(denomsum[tid] * (1.f / (float)BT), 1e-5f);
        g_s[tid] = g * (1.f / NUM_HEADS);
        s_s[tid] = g / (dn * (float)NUM_HEADS);
    }
    __syncthreads();

    const int b  = m0 >> 11;
    const int t0 = m0 & 2047;
    float acc[4][4] = {};

    for (int k0 = 0; k0 < NUM_HEADS * HEAD_DIM; k0 += 16) {
        const int h  = k0 >> 6;          // 16-wide K-chunks never straddle a head
        const int e0 = k0 & 63;
        const float sc = s_s[h];
        {
            const int r = tid >> 2, c = (tid & 3) * 4;
            const float* src = Og + (((size_t)b * NUM_HEADS + h) * T_SZ + t0 + r) * HEAD_DIM + e0 + c;
            const float4 a = *(const float4*)src;
            As[r][c + 0] = a.x * sc; As[r][c + 1] = a.y * sc;
            As[r][c + 2] = a.z * sc; As[r][c + 3] = a.w * sc;
        }
        {
            const int kk = tid >> 4, c = (tid & 15) * 4;
            const float4 w = *(const float4*)&Wo[((size_t)h * HEAD_DIM + e0 + kk) * EMBED_DIM + n0 + c];
            *(float4*)&Ws[kk][c] = w;
        }
        __syncthreads();
        #pragma unroll
        for (int kk = 0; kk < 16; ++kk) {
            float a[4], w[4];
            #pragma unroll
            for (int i = 0; i < 4; ++i) a[i] = As[ty * 4 + i][kk];
            #pragma unroll
            for (int j = 0; j < 4; ++j) w[j] = Ws[kk][tx * 4 + j];
            #pragma unroll
            for (int i = 0; i < 4; ++i)
                #pragma unroll
                for (int j = 0; j < 4; ++j) acc[i][j] += a[i] * w[j];
        }
        __syncthreads();
    }

    float bias[4] = {0.f, 0.f, 0.f, 0.f};
    for (int hh = 0; hh < NUM_HEADS; ++hh) {
        const float g = g_s[hh];
        const float* bp = bo + (size_t)hh * EMBED_DIM + n0 + tx * 4;
        #pragma unroll
        for (int j = 0; j < 4; ++j) bias[j] += g * bp[j];
    }
    #pragma unroll
    for (int i = 0; i < 4; ++i) {
        float4 v;
        v.x = acc[i][0] + bias[0]; v.y = acc[i][1] + bias[1];
        v.z = acc[i][2] + bias[2]; v.w = acc[i][3] + bias[3];
        *(float4*)&out[(size_t)(m0 + ty * 4 + i) * EMBED_DIM + n0 + tx * 4] = v;
    }
}

// ---------------------------------------------------------------------------
extern "C" void kernel_launch(void* const* d_in, const int* in_sizes, int n_in,
                              void* d_out, int out_size, void* d_ws, size_t ws_size,
                              hipStream_t stream)
{
    const float* hs   = (const float*)d_in[0];
    const float* mask = (const float*)d_in[1];
    const float* Wq   = (const float*)d_in[2];
    const float* bq   = (const float*)d_in[3];
    const float* Wk   = (const float*)d_in[4];
    const float* bk   = (const float*)d_in[5];
    const float* Wv   = (const float*)d_in[6];
    const float* bv   = (const float*)d_in[7];
    const float* Wo   = (const float*)d_in[8];
    const float* bo   = (const float*)d_in[9];
    const float* gate = (const float*)d_in[10];
    float* out = (float*)d_out;

    const size_t slab = (size_t)B_SZ * NUM_HEADS * T_SZ * HEAD_DIM;  // 4,194,304
    float* ws = (float*)d_ws;
    float* Q = ws;
    float* K = Q + slab;
    float* V = K + slab;
    float* O = V + slab;
    float* denomsum = O + slab;

    hipMemsetAsync(denomsum, 0, NUM_HEADS * sizeof(float), stream);

    qkv_proj_kernel<<<dim3(BT / 64, 3 * NUM_HEADS), 256, 0, stream>>>(
        hs, Wq, bq, Wk, bk, Wv, bv, Q, K, V);

    attn_kernel<<<dim3(T_SZ / 64, NUM_HEADS, B_SZ), 256, 0, stream>>>(
        Q, K, V, mask, O, denomsum);

    oproj_kernel<<<dim3(BT / 64, EMBED_DIM / 64), 256, 0, stream>>>(
        O, Wo, bo, gate, denomsum, out);
}

// Round 2
// 381.238 us; speedup vs baseline: 3.4935x; 3.4935x over previous
//
#include <hip/hip_runtime.h>
#include <hip/hip_bf16.h>
#include <math.h>

#define EMBED_DIM 1024
#define NUM_HEADS 16
#define HEAD_DIM  64
#define B_SZ      2
#define T_SZ      2048
#define BT        (B_SZ * T_SZ)      // 4096
#define LOG2E     1.44269504088896340736f
#define QSCALE    (0.125f * LOG2E)   // softmax scale folded with log2e into Q

typedef short bf16x8 __attribute__((ext_vector_type(8)));   // 8 bf16 in 4 VGPRs
typedef float f32x4  __attribute__((ext_vector_type(4)));

#define MFMA16(a, b, c) __builtin_amdgcn_mfma_f32_16x16x32_bf16((a), (b), (c), 0, 0, 0)

// float -> bf16 (RNE), bf16 -> float
__device__ inline short f2bf(float f) {
    unsigned u = __builtin_bit_cast(unsigned, f);
    u = (u + 0x7fffu + ((u >> 16) & 1u)) >> 16;
    return (short)u;
}
__device__ inline float bf2f(short s) {
    unsigned u = ((unsigned)(unsigned short)s) << 16;
    return __builtin_bit_cast(float, u);
}

// async global->LDS, 16B per lane; lds base must be wave-uniform (lane*16 auto)
__device__ inline void gld16(const short* g, short* lds) {
    __builtin_amdgcn_global_load_lds(
        (const __attribute__((address_space(1))) void*)g,
        (__attribute__((address_space(3))) void*)lds, 16, 0, 0);
}

// swizzled frag read from a [rows][64] bf16 tile staged with chunk c at c^(r&7)
__device__ inline bf16x8 frag_swz(const short* tile, int R, int C) {
    return *(const bf16x8*)(tile + R * 64 + ((C ^ (R & 7)) << 3));
}

__device__ inline float red_max16(float v) {
    v = fmaxf(v, __shfl_xor(v, 1)); v = fmaxf(v, __shfl_xor(v, 2));
    v = fmaxf(v, __shfl_xor(v, 4)); v = fmaxf(v, __shfl_xor(v, 8));
    return v;
}
__device__ inline float red_add16(float v) {
    v += __shfl_xor(v, 1); v += __shfl_xor(v, 2);
    v += __shfl_xor(v, 4); v += __shfl_xor(v, 8);
    return v;
}
__device__ inline float red_add64(float v) {
    v += __shfl_xor(v, 1); v += __shfl_xor(v, 2); v += __shfl_xor(v, 4);
    v += __shfl_xor(v, 8); v += __shfl_xor(v, 16); v += __shfl_xor(v, 32);
    return v;
}

// ---------------------------------------------------------------------------
// K0: convert hs -> bf16 and mask*log2e -> bf16.  grid (4096, 2) x 256
// ---------------------------------------------------------------------------
__global__ __launch_bounds__(256) void cvt_in_kernel(
    const float* __restrict__ hs, const float* __restrict__ mask,
    short* __restrict__ hsb, short* __restrict__ maskb)
{
    const long i = ((long)blockIdx.x * 256 + threadIdx.x) * 4;
    if (blockIdx.y == 0) {
        const float4 v = *(const float4*)(hs + i);
        ushort4 o; o.x = f2bf(v.x); o.y = f2bf(v.y); o.z = f2bf(v.z); o.w = f2bf(v.w);
        *(ushort4*)(hsb + i) = o;
    } else {
        const float4 v = *(const float4*)(mask + i);
        ushort4 o;
        o.x = f2bf(v.x * LOG2E); o.y = f2bf(v.y * LOG2E);
        o.z = f2bf(v.z * LOG2E); o.w = f2bf(v.w * LOG2E);
        *(ushort4*)(maskb + i) = o;
    }
}

// ---------------------------------------------------------------------------
// K1: per-head weight transposes, fp32 -> bf16.
// arr 0..2: Wq/Wk/Wv [1024][64] -> [64][1024]; arr 3: Wo [64][1024] -> [1024][64]
// grid (64, 16, 4) x 256
// ---------------------------------------------------------------------------
__global__ __launch_bounds__(256) void transpose_w_kernel(
    const float* __restrict__ Wq, const float* __restrict__ Wk,
    const float* __restrict__ Wv, const float* __restrict__ Wo,
    short* __restrict__ Wqt, short* __restrict__ Wkt,
    short* __restrict__ Wvt, short* __restrict__ WoT)
{
    const int arr = blockIdx.z, h = blockIdx.y;
    const float* src; short* dst; int R, C;
    if (arr == 0)      { src = Wq; dst = Wqt; R = 1024; C = 64; }
    else if (arr == 1) { src = Wk; dst = Wkt; R = 1024; C = 64; }
    else if (arr == 2) { src = Wv; dst = Wvt; R = 1024; C = 64; }
    else               { src = Wo; dst = WoT; R = 64;   C = 1024; }
    src += (long)h * 65536; dst += (long)h * 65536;

    const int ct = C / 32;
    const int tr = blockIdx.x / ct, tc = blockIdx.x % ct;
    __shared__ float tile[32][33];
    const int tx = threadIdx.x & 31, ty = threadIdx.x >> 5;   // 32 x 8
    #pragma unroll
    for (int i = 0; i < 4; ++i) {
        const int r = ty + 8 * i;
        tile[r][tx] = src[(long)(tr * 32 + r) * C + tc * 32 + tx];
    }
    __syncthreads();
    #pragma unroll
    for (int i = 0; i < 4; ++i) {
        const int r = ty + 8 * i;
        dst[(long)(tc * 32 + r) * R + tr * 32 + tx] = f2bf(tile[tx][r]);
    }
}

// ---------------------------------------------------------------------------
// K2: fused QKV projection, MFMA.  grid (32, 16) x 256 (4 waves, 2x2).
// BM=128, BN=192 (q|k|v for one head), BK=64.  Wave tile 64x96.
// Q written *QSCALE, layout [b,h,t,e]; K same; V written transposed [b,h,e,t].
// ---------------------------------------------------------------------------
__global__ __launch_bounds__(256) void qkv_mfma_kernel(
    const short* __restrict__ hsb,
    const short* __restrict__ Wqt, const short* __restrict__ Wkt,
    const short* __restrict__ Wvt,
    const float* __restrict__ bq, const float* __restrict__ bk,
    const float* __restrict__ bv,
    short* __restrict__ Qb, short* __restrict__ Kb, short* __restrict__ Vtb)
{
    const int m0 = blockIdx.x * 128;
    const int h  = blockIdx.y;
    __shared__ short As[128 * 64];
    __shared__ short Bs[3][64 * 64];

    const int tid = threadIdx.x, lane = tid & 63, w = tid >> 6;
    const int wm = w & 1, wn = w >> 1;
    const int quad = lane >> 4, l15 = lane & 15;

    const short* Wt0 = Wqt + (long)h * 65536;
    const short* Wt1 = Wkt + (long)h * 65536;
    const short* Wt2 = Wvt + (long)h * 65536;

    f32x4 acc[4][6] = {};

    for (int k0 = 0; k0 < 1024; k0 += 64) {
        __syncthreads();
        // stage A (128x64), 4 instrs/wave
        #pragma unroll
        for (int t = 0; t < 4; ++t) {
            const int r0 = w * 32 + t * 8;
            const int r  = r0 + (lane >> 3);
            const int cg = (lane & 7) ^ (r & 7);
            gld16(hsb + (long)(m0 + r) * 1024 + k0 + cg * 8, &As[r0 * 64]);
        }
        // stage B (3 x 64x64), 6 instrs/wave
        #pragma unroll
        for (int t = 0; t < 2; ++t) {
            const int r0 = w * 16 + t * 8;
            const int r  = r0 + (lane >> 3);
            const int cg = (lane & 7) ^ (r & 7);
            gld16(Wt0 + (long)r * 1024 + k0 + cg * 8, &Bs[0][r0 * 64]);
            gld16(Wt1 + (long)r * 1024 + k0 + cg * 8, &Bs[1][r0 * 64]);
            gld16(Wt2 + (long)r * 1024 + k0 + cg * 8, &Bs[2][r0 * 64]);
        }
        __syncthreads();
        #pragma unroll
        for (int ks = 0; ks < 2; ++ks) {
            bf16x8 af[4];
            #pragma unroll
            for (int ms = 0; ms < 4; ++ms)
                af[ms] = frag_swz(As, wm * 64 + ms * 16 + l15, ks * 4 + quad);
            #pragma unroll
            for (int ns = 0; ns < 6; ++ns) {
                const int gn  = wn * 6 + ns;
                const int arr = gn >> 2;
                const bf16x8 bfr = frag_swz(&Bs[arr][0], (gn & 3) * 16 + l15, ks * 4 + quad);
                #pragma unroll
                for (int ms = 0; ms < 4; ++ms)
                    acc[ms][ns] = MFMA16(af[ms], bfr, acc[ms][ns]);
            }
        }
    }

    // epilogue
    #pragma unroll
    for (int ns = 0; ns < 6; ++ns) {
        const int gn  = wn * 6 + ns;
        const int arr = gn >> 2;
        const int e   = (gn & 3) * 16 + l15;
        const float bias = (arr == 0 ? bq : arr == 1 ? bk : bv)[h * 64 + e];
        #pragma unroll
        for (int ms = 0; ms < 4; ++ms) {
            const int mbase = m0 + wm * 64 + ms * 16 + quad * 4;
            const int bb = mbase >> 11, t0 = mbase & 2047;
            if (arr == 2) {
                ushort4 pk;
                pk.x = (unsigned short)f2bf(acc[ms][ns][0] + bias);
                pk.y = (unsigned short)f2bf(acc[ms][ns][1] + bias);
                pk.z = (unsigned short)f2bf(acc[ms][ns][2] + bias);
                pk.w = (unsigned short)f2bf(acc[ms][ns][3] + bias);
                *(ushort4*)&Vtb[((long)(bb * 16 + h) * 64 + e) * 2048 + t0] = pk;
            } else {
                #pragma unroll
                for (int r = 0; r < 4; ++r) {
                    const float v = acc[ms][ns][r] + bias;
                    const long off = ((long)(bb * 16 + h) * 2048 + (t0 + r)) * 64 + e;
                    if (arr == 0) Qb[off] = f2bf(v * QSCALE);
                    else          Kb[off] = f2bf(v);
                }
            }
        }
    }
}

// ---------------------------------------------------------------------------
// K3: flash attention, MFMA, log2-domain softmax.  grid (16, 16, 2) x 256.
// BQ=128 (32 q-rows/wave), KV tiles of 64. Q frags register-resident.
// Writes O (bf16, [b][t][h*64+e]) and row-norm sums -> denomsum[h].
// ---------------------------------------------------------------------------
__global__ __launch_bounds__(256) void attn_mfma_kernel(
    const short* __restrict__ Qb, const short* __restrict__ Kb,
    const short* __restrict__ Vtb, const short* __restrict__ maskb,
    short* __restrict__ Ob, float* __restrict__ denomsum)
{
    const int q0 = blockIdx.x * 128;
    const int h  = blockIdx.y, b = blockIdx.z;
    const long bh = ((long)b * 16 + h) * (long)T_SZ * 64;

    __shared__ short Ks[64 * 64];
    __shared__ short Vs[64 * 64];
    __shared__ short Ps[4][32 * 72];    // per-wave private P, stride 72 (16B-aligned rows)
    __shared__ float wred[4];

    const int tid = threadIdx.x, lane = tid & 63, w = tid >> 6;
    const int quad = lane >> 4, l15 = lane & 15;
    short* Pw = &Ps[w][0];

    // register-resident Q fragments (global offsets are 16B aligned)
    bf16x8 qf[2][2];
    #pragma unroll
    for (int ms = 0; ms < 2; ++ms)
        #pragma unroll
        for (int ks = 0; ks < 2; ++ks)
            qf[ms][ks] = *(const bf16x8*)(Qb + bh +
                (long)(q0 + w * 32 + ms * 16 + l15) * 64 + ks * 32 + quad * 8);

    f32x4 o[2][4] = {};
    float m2[2][4], l[2][4];
    #pragma unroll
    for (int ms = 0; ms < 2; ++ms)
        #pragma unroll
        for (int r = 0; r < 4; ++r) { m2[ms][r] = -3.0e38f; l[ms][r] = 0.f; }

    const short* Kg = Kb + bh;
    const short* Vg = Vtb + bh;   // [64][2048]

    for (int kt = 0; kt < 32; ++kt) {
        const int kv0 = kt * 64;
        __syncthreads();
        #pragma unroll
        for (int t = 0; t < 2; ++t) {
            const int r0 = w * 16 + t * 8;
            const int r  = r0 + (lane >> 3);
            const int cg = (lane & 7) ^ (r & 7);
            gld16(Kg + (long)(kv0 + r) * 64 + cg * 8, &Ks[r0 * 64]);
            gld16(Vg + (long)r * 2048 + kv0 + cg * 8, &Vs[r0 * 64]);
        }
        __syncthreads();

        // S = Q K^T  (scores already in log2 domain via QSCALE)
        f32x4 s[2][4] = {};
        #pragma unroll
        for (int ks = 0; ks < 2; ++ks)
            #pragma unroll
            for (int ns = 0; ns < 4; ++ns) {
                const bf16x8 kf = frag_swz(Ks, ns * 16 + l15, ks * 4 + quad);
                s[0][ns] = MFMA16(qf[0][ks], kf, s[0][ns]);
                s[1][ns] = MFMA16(qf[1][ks], kf, s[1][ns]);
            }

        // + mask*log2e
        #pragma unroll
        for (int ms = 0; ms < 2; ++ms) {
            const int qrow = q0 + w * 32 + ms * 16 + quad * 4;
            #pragma unroll
            for (int ns = 0; ns < 4; ++ns) {
                const short* mrow = maskb + (long)qrow * 2048 + kv0 + ns * 16 + l15;
                #pragma unroll
                for (int r = 0; r < 4; ++r)
                    s[ms][ns][r] += bf2f(mrow[(long)r * 2048]);
            }
        }

        // online softmax (base-2)
        #pragma unroll
        for (int ms = 0; ms < 2; ++ms) {
            #pragma unroll
            for (int r = 0; r < 4; ++r) {
                float v = fmaxf(fmaxf(s[ms][0][r], s[ms][1][r]),
                                fmaxf(s[ms][2][r], s[ms][3][r]));
                v = red_max16(v);
                const float mn = fmaxf(m2[ms][r], v);
                const float al = exp2f(m2[ms][r] - mn);
                m2[ms][r] = mn;
                l[ms][r] *= al;
                #pragma unroll
                for (int ns = 0; ns < 4; ++ns) o[ms][ns][r] *= al;
                float rs = 0.f;
                #pragma unroll
                for (int ns = 0; ns < 4; ++ns) {
                    const float p = exp2f(s[ms][ns][r] - mn);
                    Pw[(ms * 16 + quad * 4 + r) * 72 + ns * 16 + l15] = f2bf(p);
                    rs += p;
                }
                l[ms][r] += red_add16(rs);
            }
        }

        // O += P V   (P is wave-private; compiler inserts the lgkm wait)
        #pragma unroll
        for (int ks = 0; ks < 2; ++ks) {
            bf16x8 pf[2];
            #pragma unroll
            for (int ms = 0; ms < 2; ++ms)
                pf[ms] = *(const bf16x8*)&Pw[(ms * 16 + l15) * 72 + ks * 64 / 2 + quad * 8];
            #pragma unroll
            for (int ns = 0; ns < 4; ++ns) {
                const bf16x8 vf = frag_swz(Vs, ns * 16 + l15, ks * 4 + quad);
                o[0][ns] = MFMA16(pf[0], vf, o[0][ns]);
                o[1][ns] = MFMA16(pf[1], vf, o[1][ns]);
            }
        }
    }

    // epilogue: normalize, write O, reduce row L2 norms
    float wnorm = 0.f;
    #pragma unroll
    for (int ms = 0; ms < 2; ++ms)
        #pragma unroll
        for (int r = 0; r < 4; ++r) {
            const float inv = 1.f / l[ms][r];
            float ssp = 0.f;
            #pragma unroll
            for (int ns = 0; ns < 4; ++ns) {
                const float v = o[ms][ns][r] * inv;
                o[ms][ns][r] = v;
                ssp += v * v;
            }
            wnorm += sqrtf(red_add16(ssp));
        }
    wnorm = red_add64(wnorm) * (1.f / 16.f);   // each row counted by 16 lanes
    if (lane == 0) wred[w] = wnorm;

    #pragma unroll
    for (int ms = 0; ms < 2; ++ms) {
        const int t = q0 + w * 32 + ms * 16 + quad * 4;
        #pragma unroll
        for (int ns = 0; ns < 4; ++ns) {
            const int e = ns * 16 + l15;
            #pragma unroll
            for (int r = 0; r < 4; ++r)
                Ob[((long)(b * 2048 + t + r)) * 1024 + h * 64 + e] = f2bf(o[ms][ns][r]);
        }
    }
    __syncthreads();
    if (tid == 0)
        atomicAdd(&denomsum[h], wred[0] + wred[1] + wred[2] + wred[3]);
}

// ---------------------------------------------------------------------------
// K4: scale O rows by g_h / (denom_h * H), in place.  grid 4096 x 256
// ---------------------------------------------------------------------------
__global__ __launch_bounds__(256) void scale_o_kernel(
    short* __restrict__ Ob, const float* __restrict__ denomsum,
    const float* __restrict__ gate)
{
    __shared__ float sh[16];
    if (threadIdx.x < 16) {
        const float g  = fminf(fmaxf(gate[threadIdx.x], 0.f), 1.f);
        const float dn = fmaxf(denomsum[threadIdx.x] * (1.f / (float)BT), 1e-5f);
        sh[threadIdx.x] = g / (dn * (float)NUM_HEADS);
    }
    __syncthreads();
    const long i = ((long)blockIdx.x * 256 + threadIdx.x) * 4;
    const int hh = (int)((i >> 6) & 15);
    const float sc = sh[hh];
    ushort4 v = *(ushort4*)(Ob + i);
    v.x = (unsigned short)f2bf(bf2f((short)v.x) * sc);
    v.y = (unsigned short)f2bf(bf2f((short)v.y) * sc);
    v.z = (unsigned short)f2bf(bf2f((short)v.z) * sc);
    v.w = (unsigned short)f2bf(bf2f((short)v.w) * sc);
    *(ushort4*)(Ob + i) = v;
}

// ---------------------------------------------------------------------------
// K5: output projection, MFMA.  grid (32, 8) x 256 (2x2 waves, wave 64x64).
// BM=128, BN=128, BK=64 (= one head per k-iter).  Bias folded in epilogue.
// ---------------------------------------------------------------------------
__global__ __launch_bounds__(256) void oproj_mfma_kernel(
    const short* __restrict__ Ob,    // [4096][1024] pre-scaled
    const short* __restrict__ WoT,   // [16][1024][64]
    const float* __restrict__ bo,    // [16][1024]
    const float* __restrict__ gate,
    float* __restrict__ out)         // [4096][1024]
{
    const int m0 = blockIdx.x * 128;
    const int n0 = blockIdx.y * 128;
    __shared__ short As[128 * 64];
    __shared__ short Bs[128 * 64];

    const int tid = threadIdx.x, lane = tid & 63, w = tid >> 6;
    const int wm = w & 1, wn = w >> 1;
    const int quad = lane >> 4, l15 = lane & 15;

    f32x4 acc[4][4] = {};

    for (int h = 0; h < 16; ++h) {
        __syncthreads();
        #pragma unroll
        for (int t = 0; t < 4; ++t) {
            const int r0 = w * 32 + t * 8;
            const int r  = r0 + (lane >> 3);
            const int cg = (lane & 7) ^ (r & 7);
            gld16(Ob + (long)(m0 + r) * 1024 + h * 64 + cg * 8, &As[r0 * 64]);
            gld16(WoT + (long)h * 65536 + (long)(n0 + r) * 64 + cg * 8, &Bs[r0 * 64]);
        }
        __syncthreads();
        #pragma unroll
        for (int ks = 0; ks < 2; ++ks) {
            bf16x8 af[4];
            #pragma unroll
            for (int ms = 0; ms < 4; ++ms)
                af[ms] = frag_swz(As, wm * 64 + ms * 16 + l15, ks * 4 + quad);
            #pragma unroll
            for (int ns = 0; ns < 4; ++ns) {
                const bf16x8 bfr = frag_swz(Bs, wn * 64 + ns * 16 + l15, ks * 4 + quad);
                #pragma unroll
                for (int ms = 0; ms < 4; ++ms)
                    acc[ms][ns] = MFMA16(af[ms], bfr, acc[ms][ns]);
            }
        }
    }

    // epilogue: bias_eff[n] = sum_h clamp(g_h)*bo[h][n]/16
    float gcl[16];
    #pragma unroll
    for (int hh = 0; hh < 16; ++hh)
        gcl[hh] = fminf(fmaxf(gate[hh], 0.f), 1.f) * (1.f / (float)NUM_HEADS);

    #pragma unroll
    for (int ns = 0; ns < 4; ++ns) {
        const int n = n0 + wn * 64 + ns * 16 + l15;
        float be = 0.f;
        #pragma unroll
        for (int hh = 0; hh < 16; ++hh) be += gcl[hh] * bo[hh * 1024 + n];
        #pragma unroll
        for (int ms = 0; ms < 4; ++ms) {
            const int m = m0 + wm * 64 + ms * 16 + quad * 4;
            #pragma unroll
            for (int r = 0; r < 4; ++r)
                out[(long)(m + r) * 1024 + n] = acc[ms][ns][r] + be;
        }
    }
}

// ---------------------------------------------------------------------------
extern "C" void kernel_launch(void* const* d_in, const int* in_sizes, int n_in,
                              void* d_out, int out_size, void* d_ws, size_t ws_size,
                              hipStream_t stream)
{
    const float* hs   = (const float*)d_in[0];
    const float* mask = (const float*)d_in[1];
    const float* Wq   = (const float*)d_in[2];
    const float* bq   = (const float*)d_in[3];
    const float* Wk   = (const float*)d_in[4];
    const float* bk   = (const float*)d_in[5];
    const float* Wv   = (const float*)d_in[6];
    const float* bv   = (const float*)d_in[7];
    const float* Wo   = (const float*)d_in[8];
    const float* bo   = (const float*)d_in[9];
    const float* gate = (const float*)d_in[10];
    float* out = (float*)d_out;

    char* ws = (char*)d_ws;
    const size_t MB = 1024 * 1024;
    short* hsb   = (short*)(ws);                 // 8 MB  (4096x1024)
    short* maskb = (short*)(ws + 8  * MB);       // 8 MB  (2048x2048)
    short* Wqt   = (short*)(ws + 16 * MB);       // 2 MB  (16x64x1024)
    short* Wkt   = (short*)(ws + 18 * MB);       // 2 MB
    short* Wvt   = (short*)(ws + 20 * MB);       // 2 MB
    short* WoT   = (short*)(ws + 22 * MB);       // 2 MB  (16x1024x64)
    short* Qb    = (short*)(ws + 24 * MB);       // 8 MB  [b,h,t,e]
    short* Kb    = (short*)(ws + 32 * MB);       // 8 MB  [b,h,t,e]
    short* Vtb   = (short*)(ws + 40 * MB);       // 8 MB  [b,h,e,t]
    short* Ob    = (short*)(ws + 48 * MB);       // 8 MB  [b,t,h*64+e]
    float* denomsum = (float*)(ws + 56 * MB);    // 16 floats

    hipMemsetAsync(denomsum, 0, NUM_HEADS * sizeof(float), stream);

    cvt_in_kernel<<<dim3(4096, 2), 256, 0, stream>>>(hs, mask, hsb, maskb);
    transpose_w_kernel<<<dim3(64, 16, 4), 256, 0, stream>>>(
        Wq, Wk, Wv, Wo, Wqt, Wkt, Wvt, WoT);
    qkv_mfma_kernel<<<dim3(32, 16), 256, 0, stream>>>(
        hsb, Wqt, Wkt, Wvt, bq, bk, bv, Qb, Kb, Vtb);
    attn_mfma_kernel<<<dim3(16, 16, 2), 256, 0, stream>>>(
        Qb, Kb, Vtb, maskb, Ob, denomsum);
    scale_o_kernel<<<4096, 256, 0, stream>>>(Ob, denomsum, gate);
    oproj_mfma_kernel<<<dim3(32, 8), 256, 0, stream>>>(
        Ob, WoT, bo, gate, out);
}

// Round 3
// 295.358 us; speedup vs baseline: 4.5093x; 1.2908x over previous
//
#include <hip/hip_runtime.h>
#include <hip/hip_bf16.h>
#include <math.h>

#define EMBED_DIM 1024
#define NUM_HEADS 16
#define HEAD_DIM  64
#define B_SZ      2
#define T_SZ      2048
#define BT        (B_SZ * T_SZ)      // 4096
#define LOG2E     1.44269504088896340736f
#define QSCALE    (0.125f * LOG2E)   // softmax scale folded with log2e into Q

typedef short bf16x8 __attribute__((ext_vector_type(8)));   // 8 bf16 in 4 VGPRs
typedef float f32x4  __attribute__((ext_vector_type(4)));

#define MFMA16(a, b, c) __builtin_amdgcn_mfma_f32_16x16x32_bf16((a), (b), (c), 0, 0, 0)

// float -> bf16 (RNE), bf16 -> float
__device__ inline short f2bf(float f) {
    unsigned u = __builtin_bit_cast(unsigned, f);
    u = (u + 0x7fffu + ((u >> 16) & 1u)) >> 16;
    return (short)u;
}
__device__ inline float bf2f(short s) {
    unsigned u = ((unsigned)(unsigned short)s) << 16;
    return __builtin_bit_cast(float, u);
}
// pack two f32 -> bf16x2 in one u32 (packed cvt when HW has it)
__device__ inline unsigned pk2(float a, float b) {
#if __has_builtin(__builtin_amdgcn_cvt_pk_bf16_f32)
    typedef __bf16 bf2_t __attribute__((ext_vector_type(2)));
    bf2_t t = __builtin_amdgcn_cvt_pk_bf16_f32(a, b);
    return __builtin_bit_cast(unsigned, t);
#else
    return (unsigned)(unsigned short)f2bf(a) | ((unsigned)(unsigned short)f2bf(b) << 16);
#endif
}

// async global->LDS, 16B per lane; lds base must be wave-uniform (lane*16 auto)
__device__ inline void gld16(const short* g, short* lds) {
    __builtin_amdgcn_global_load_lds(
        (const __attribute__((address_space(1))) void*)g,
        (__attribute__((address_space(3))) void*)lds, 16, 0, 0);
}

// swizzled frag read from a [rows][64] bf16 tile staged with chunk c at c^(r&7)
__device__ inline bf16x8 frag_swz(const short* tile, int R, int C) {
    return *(const bf16x8*)(tile + R * 64 + ((C ^ (R & 7)) << 3));
}

__device__ inline float red_add64(float v) {
    v += __shfl_xor(v, 1); v += __shfl_xor(v, 2); v += __shfl_xor(v, 4);
    v += __shfl_xor(v, 8); v += __shfl_xor(v, 16); v += __shfl_xor(v, 32);
    return v;
}

// ---------------------------------------------------------------------------
// K0: convert hs -> bf16 and mask*log2e -> bf16.  grid (4096, 2) x 256
// ---------------------------------------------------------------------------
__global__ __launch_bounds__(256) void cvt_in_kernel(
    const float* __restrict__ hs, const float* __restrict__ mask,
    short* __restrict__ hsb, short* __restrict__ maskb)
{
    const long i = ((long)blockIdx.x * 256 + threadIdx.x) * 4;
    if (blockIdx.y == 0) {
        const float4 v = *(const float4*)(hs + i);
        ushort4 o; o.x = f2bf(v.x); o.y = f2bf(v.y); o.z = f2bf(v.z); o.w = f2bf(v.w);
        *(ushort4*)(hsb + i) = o;
    } else {
        const float4 v = *(const float4*)(mask + i);
        ushort4 o;
        o.x = f2bf(v.x * LOG2E); o.y = f2bf(v.y * LOG2E);
        o.z = f2bf(v.z * LOG2E); o.w = f2bf(v.w * LOG2E);
        *(ushort4*)(maskb + i) = o;
    }
}

// ---------------------------------------------------------------------------
// K1: per-head weight transposes, fp32 -> bf16.
// arr 0..2: Wq/Wk/Wv [1024][64] -> [64][1024]; arr 3: Wo [64][1024] -> [1024][64]
// grid (64, 16, 4) x 256
// ---------------------------------------------------------------------------
__global__ __launch_bounds__(256) void transpose_w_kernel(
    const float* __restrict__ Wq, const float* __restrict__ Wk,
    const float* __restrict__ Wv, const float* __restrict__ Wo,
    short* __restrict__ Wqt, short* __restrict__ Wkt,
    short* __restrict__ Wvt, short* __restrict__ WoT)
{
    const int arr = blockIdx.z, h = blockIdx.y;
    const float* src; short* dst; int R, C;
    if (arr == 0)      { src = Wq; dst = Wqt; R = 1024; C = 64; }
    else if (arr == 1) { src = Wk; dst = Wkt; R = 1024; C = 64; }
    else if (arr == 2) { src = Wv; dst = Wvt; R = 1024; C = 64; }
    else               { src = Wo; dst = WoT; R = 64;   C = 1024; }
    src += (long)h * 65536; dst += (long)h * 65536;

    const int ct = C / 32;
    const int tr = blockIdx.x / ct, tc = blockIdx.x % ct;
    __shared__ float tile[32][33];
    const int tx = threadIdx.x & 31, ty = threadIdx.x >> 5;   // 32 x 8
    #pragma unroll
    for (int i = 0; i < 4; ++i) {
        const int r = ty + 8 * i;
        tile[r][tx] = src[(long)(tr * 32 + r) * C + tc * 32 + tx];
    }
    __syncthreads();
    #pragma unroll
    for (int i = 0; i < 4; ++i) {
        const int r = ty + 8 * i;
        dst[(long)(tc * 32 + r) * R + tr * 32 + tx] = f2bf(tile[tx][r]);
    }
}

// ---------------------------------------------------------------------------
// K2: fused QKV projection, MFMA.  grid (32, 16) x 256 (4 waves, 2x2).
// BM=128, BN=192 (q|k|v for one head), BK=64.  Wave tile 64x96.
// Q written *QSCALE, layout [b,h,t,e]; K same; V written transposed [b,h,e,t']
// with t' = kv-permutation within each 64-tile so attention's PV A-frags are
// contiguous b128 reads: t' = (t&~63)|(t&35)|((t&12)<<1)|((t&16)>>2).
// ---------------------------------------------------------------------------
__global__ __launch_bounds__(256) void qkv_mfma_kernel(
    const short* __restrict__ hsb,
    const short* __restrict__ Wqt, const short* __restrict__ Wkt,
    const short* __restrict__ Wvt,
    const float* __restrict__ bq, const float* __restrict__ bk,
    const float* __restrict__ bv,
    short* __restrict__ Qb, short* __restrict__ Kb, short* __restrict__ Vtb)
{
    const int m0 = blockIdx.x * 128;
    const int h  = blockIdx.y;
    __shared__ short As[128 * 64];
    __shared__ short Bs[3][64 * 64];

    const int tid = threadIdx.x, lane = tid & 63, w = tid >> 6;
    const int wm = w & 1, wn = w >> 1;
    const int quad = lane >> 4, l15 = lane & 15;

    const short* Wt0 = Wqt + (long)h * 65536;
    const short* Wt1 = Wkt + (long)h * 65536;
    const short* Wt2 = Wvt + (long)h * 65536;

    f32x4 acc[4][6] = {};

    for (int k0 = 0; k0 < 1024; k0 += 64) {
        __syncthreads();
        // stage A (128x64), 4 instrs/wave
        #pragma unroll
        for (int t = 0; t < 4; ++t) {
            const int r0 = w * 32 + t * 8;
            const int r  = r0 + (lane >> 3);
            const int cg = (lane & 7) ^ (r & 7);
            gld16(hsb + (long)(m0 + r) * 1024 + k0 + cg * 8, &As[r0 * 64]);
        }
        // stage B (3 x 64x64), 6 instrs/wave
        #pragma unroll
        for (int t = 0; t < 2; ++t) {
            const int r0 = w * 16 + t * 8;
            const int r  = r0 + (lane >> 3);
            const int cg = (lane & 7) ^ (r & 7);
            gld16(Wt0 + (long)r * 1024 + k0 + cg * 8, &Bs[0][r0 * 64]);
            gld16(Wt1 + (long)r * 1024 + k0 + cg * 8, &Bs[1][r0 * 64]);
            gld16(Wt2 + (long)r * 1024 + k0 + cg * 8, &Bs[2][r0 * 64]);
        }
        __syncthreads();
        #pragma unroll
        for (int ks = 0; ks < 2; ++ks) {
            bf16x8 af[4];
            #pragma unroll
            for (int ms = 0; ms < 4; ++ms)
                af[ms] = frag_swz(As, wm * 64 + ms * 16 + l15, ks * 4 + quad);
            #pragma unroll
            for (int ns = 0; ns < 6; ++ns) {
                const int gn  = wn * 6 + ns;
                const int arr = gn >> 2;
                const bf16x8 bfr = frag_swz(&Bs[arr][0], (gn & 3) * 16 + l15, ks * 4 + quad);
                #pragma unroll
                for (int ms = 0; ms < 4; ++ms)
                    acc[ms][ns] = MFMA16(af[ms], bfr, acc[ms][ns]);
            }
        }
    }

    // epilogue
    #pragma unroll
    for (int ns = 0; ns < 6; ++ns) {
        const int gn  = wn * 6 + ns;
        const int arr = gn >> 2;
        const int e   = (gn & 3) * 16 + l15;
        const float bias = (arr == 0 ? bq : arr == 1 ? bk : bv)[h * 64 + e];
        #pragma unroll
        for (int ms = 0; ms < 4; ++ms) {
            const int mbase = m0 + wm * 64 + ms * 16 + quad * 4;
            const int bb = mbase >> 11, t0 = mbase & 2047;
            if (arr == 2) {
                const int tp = (t0 & ~63) | (t0 & 35) | ((t0 & 12) << 1) | ((t0 & 16) >> 2);
                ushort4 pk;
                pk.x = (unsigned short)f2bf(acc[ms][ns][0] + bias);
                pk.y = (unsigned short)f2bf(acc[ms][ns][1] + bias);
                pk.z = (unsigned short)f2bf(acc[ms][ns][2] + bias);
                pk.w = (unsigned short)f2bf(acc[ms][ns][3] + bias);
                *(ushort4*)&Vtb[((long)(bb * 16 + h) * 64 + e) * 2048 + tp] = pk;
            } else {
                #pragma unroll
                for (int r = 0; r < 4; ++r) {
                    const float v = acc[ms][ns][r] + bias;
                    const long off = ((long)(bb * 16 + h) * 2048 + (t0 + r)) * 64 + e;
                    if (arr == 0) Qb[off] = f2bf(v * QSCALE);
                    else          Kb[off] = f2bf(v);
                }
            }
        }
    }
}

// ---------------------------------------------------------------------------
// K3: flash attention, transposed-S formulation.  grid (16, 16, 2) x 256.
// S^T = K·Q^T  (row = kv = quad*4+r, col = q = lane&15)  ->  softmax rows are
// lane-local (+2 shfl over quads).  P^T stays in registers as the PV B-operand
// via a custom k<->kv bijection (V pre-permuted at QKV time).  O accumulated
// transposed.  No P LDS round-trip.
// ---------------------------------------------------------------------------
__global__ __launch_bounds__(256) void attn_mfma_kernel(
    const short* __restrict__ Qb, const short* __restrict__ Kb,
    const short* __restrict__ Vtb, const short* __restrict__ maskb,
    short* __restrict__ Ob, float* __restrict__ denomsum)
{
    const int q0 = blockIdx.x * 128;
    const int h  = blockIdx.y, b = blockIdx.z;
    const long bh = ((long)b * 16 + h) * (long)T_SZ * 64;

    __shared__ short Ks[64 * 64];
    __shared__ short Vs[64 * 64];
    __shared__ float wred[4];

    const int tid = threadIdx.x, lane = tid & 63, w = tid >> 6;
    const int quad = lane >> 4, l15 = lane & 15;

    // Q fragments (used as B-operand of K·Q^T): lane holds q-row = l15
    bf16x8 qf[2][2];
    #pragma unroll
    for (int ms = 0; ms < 2; ++ms)
        #pragma unroll
        for (int ks = 0; ks < 2; ++ks)
            qf[ms][ks] = *(const bf16x8*)(Qb + bh +
                (long)(q0 + w * 32 + ms * 16 + l15) * 64 + ks * 32 + quad * 8);

    f32x4 o[2][4] = {};                 // O^T: row e = quad*4+r (per eb), col q = l15
    float m2[2] = {-3.0e38f, -3.0e38f}; // per-lane row (q=l15) running max (log2)
    float lp[2] = {0.f, 0.f};           // per-lane partial row sum (this quad's kv)

    const short* Kg = Kb + bh;
    const short* Vg = Vtb + bh;   // [64 e][2048 t'] (kv-permuted within 64-tiles)

    for (int kt = 0; kt < 32; ++kt) {
        const int kv0 = kt * 64;
        __syncthreads();
        #pragma unroll
        for (int t = 0; t < 2; ++t) {
            const int r0 = w * 16 + t * 8;
            const int r  = r0 + (lane >> 3);
            const int cg = (lane & 7) ^ (r & 7);
            gld16(Kg + (long)(kv0 + r) * 64 + cg * 8, &Ks[r0 * 64]);
            gld16(Vg + (long)r * 2048 + kv0 + cg * 8, &Vs[r0 * 64]);
        }
        __syncthreads();

        // S^T = K Q^T : s[ms][kb] holds kv = kv0+kb*16+quad*4+r, q = l15
        f32x4 s[2][4] = {};
        #pragma unroll
        for (int ks = 0; ks < 2; ++ks) {
            bf16x8 kf[4];
            #pragma unroll
            for (int kb = 0; kb < 4; ++kb)
                kf[kb] = frag_swz(Ks, kb * 16 + l15, ks * 4 + quad);
            #pragma unroll
            for (int kb = 0; kb < 4; ++kb) {
                s[0][kb] = MFMA16(kf[kb], qf[0][ks], s[0][kb]);
                s[1][kb] = MFMA16(kf[kb], qf[1][ks], s[1][kb]);
            }
        }

        // + mask*log2e : contiguous ushort4 per (ms,kb)
        #pragma unroll
        for (int ms = 0; ms < 2; ++ms) {
            const short* mrow = maskb +
                (long)(q0 + w * 32 + ms * 16 + l15) * 2048 + kv0 + quad * 4;
            #pragma unroll
            for (int kb = 0; kb < 4; ++kb) {
                const ushort4 mv = *(const ushort4*)(mrow + kb * 16);
                s[ms][kb][0] += bf2f((short)mv.x);
                s[ms][kb][1] += bf2f((short)mv.y);
                s[ms][kb][2] += bf2f((short)mv.z);
                s[ms][kb][3] += bf2f((short)mv.w);
            }
        }

        // online softmax (base-2), rows lane-local
        bf16x8 pb[2][2];
        #pragma unroll
        for (int ms = 0; ms < 2; ++ms) {
            float mx = s[ms][0][0];
            #pragma unroll
            for (int kb = 0; kb < 4; ++kb)
                #pragma unroll
                for (int r = 0; r < 4; ++r) mx = fmaxf(mx, s[ms][kb][r]);
            mx = fmaxf(mx, __shfl_xor(mx, 16));
            mx = fmaxf(mx, __shfl_xor(mx, 32));
            const float mn = fmaxf(m2[ms], mx);
            const float al = exp2f(m2[ms] - mn);
            m2[ms] = mn;
            #pragma unroll
            for (int eb = 0; eb < 4; ++eb) o[ms][eb] *= al;
            float rs = 0.f;
            unsigned w0[4], w1[4];
            #pragma unroll
            for (int kb = 0; kb < 4; ++kb) {
                const float p0 = exp2f(s[ms][kb][0] - mn);
                const float p1 = exp2f(s[ms][kb][1] - mn);
                const float p2 = exp2f(s[ms][kb][2] - mn);
                const float p3 = exp2f(s[ms][kb][3] - mn);
                rs += (p0 + p1) + (p2 + p3);
                w0[kb] = pk2(p0, p1);
                w1[kb] = pk2(p2, p3);
            }
            lp[ms] = lp[ms] * al + rs;
            #pragma unroll
            for (int kbp = 0; kbp < 2; ++kbp) {
                const uint4 u = {w0[2 * kbp], w1[2 * kbp], w0[2 * kbp + 1], w1[2 * kbp + 1]};
                pb[ms][kbp] = __builtin_bit_cast(bf16x8, u);
            }
        }

        // O^T += V^T P^T  (K=32 MFMA, custom k<->kv bijection; V pre-permuted)
        #pragma unroll
        for (int kbp = 0; kbp < 2; ++kbp)
            #pragma unroll
            for (int eb = 0; eb < 4; ++eb) {
                const bf16x8 va = frag_swz(Vs, eb * 16 + l15, kbp * 4 + quad);
                o[0][eb] = MFMA16(va, pb[0][kbp], o[0][eb]);
                o[1][eb] = MFMA16(va, pb[1][kbp], o[1][eb]);
            }
    }

    // epilogue: finish row sums, normalize, write O^T, row-norm reduction
    float tot = 0.f;
    #pragma unroll
    for (int ms = 0; ms < 2; ++ms) {
        float lf = lp[ms];
        lf += __shfl_xor(lf, 16);
        lf += __shfl_xor(lf, 32);
        const float inv = 1.f / lf;
        float ss = 0.f;
        #pragma unroll
        for (int eb = 0; eb < 4; ++eb) {
            o[ms][eb] *= inv;
            #pragma unroll
            for (int r = 0; r < 4; ++r) ss += o[ms][eb][r] * o[ms][eb][r];
        }
        ss += __shfl_xor(ss, 16);
        ss += __shfl_xor(ss, 32);
        tot += sqrtf(ss);

        const int q = q0 + w * 32 + ms * 16 + l15;
        #pragma unroll
        for (int eb = 0; eb < 4; ++eb) {
            uint2 pk;
            pk.x = pk2(o[ms][eb][0], o[ms][eb][1]);
            pk.y = pk2(o[ms][eb][2], o[ms][eb][3]);
            *(uint2*)&Ob[((long)(b * 2048 + q)) * 1024 + h * 64 + eb * 16 + quad * 4] = pk;
        }
    }
    // each row's norm appears in 4 lanes (quads): sum all, divide by 4
    const float wsum = red_add64(tot) * 0.25f;
    if (lane == 0) wred[w] = wsum;
    __syncthreads();
    if (tid == 0)
        atomicAdd(&denomsum[h], wred[0] + wred[1] + wred[2] + wred[3]);
}

// ---------------------------------------------------------------------------
// K4: scale O rows by g_h / (denom_h * H), in place.  grid 4096 x 256
// ---------------------------------------------------------------------------
__global__ __launch_bounds__(256) void scale_o_kernel(
    short* __restrict__ Ob, const float* __restrict__ denomsum,
    const float* __restrict__ gate)
{
    __shared__ float sh[16];
    if (threadIdx.x < 16) {
        const float g  = fminf(fmaxf(gate[threadIdx.x], 0.f), 1.f);
        const float dn = fmaxf(denomsum[threadIdx.x] * (1.f / (float)BT), 1e-5f);
        sh[threadIdx.x] = g / (dn * (float)NUM_HEADS);
    }
    __syncthreads();
    const long i = ((long)blockIdx.x * 256 + threadIdx.x) * 4;
    const int hh = (int)((i >> 6) & 15);
    const float sc = sh[hh];
    ushort4 v = *(ushort4*)(Ob + i);
    v.x = (unsigned short)f2bf(bf2f((short)v.x) * sc);
    v.y = (unsigned short)f2bf(bf2f((short)v.y) * sc);
    v.z = (unsigned short)f2bf(bf2f((short)v.z) * sc);
    v.w = (unsigned short)f2bf(bf2f((short)v.w) * sc);
    *(ushort4*)(Ob + i) = v;
}

// ---------------------------------------------------------------------------
// K5: output projection, MFMA.  grid (32, 8) x 256 (2x2 waves, wave 64x64).
// BM=128, BN=128, BK=64 (= one head per k-iter).  Bias folded in epilogue.
// ---------------------------------------------------------------------------
__global__ __launch_bounds__(256) void oproj_mfma_kernel(
    const short* __restrict__ Ob,    // [4096][1024] pre-scaled
    const short* __restrict__ WoT,   // [16][1024][64]
    const float* __restrict__ bo,    // [16][1024]
    const float* __restrict__ gate,
    float* __restrict__ out)         // [4096][1024]
{
    const int m0 = blockIdx.x * 128;
    const int n0 = blockIdx.y * 128;
    __shared__ short As[128 * 64];
    __shared__ short Bs[128 * 64];

    const int tid = threadIdx.x, lane = tid & 63, w = tid >> 6;
    const int wm = w & 1, wn = w >> 1;
    const int quad = lane >> 4, l15 = lane & 15;

    f32x4 acc[4][4] = {};

    for (int h = 0; h < 16; ++h) {
        __syncthreads();
        #pragma unroll
        for (int t = 0; t < 4; ++t) {
            const int r0 = w * 32 + t * 8;
            const int r  = r0 + (lane >> 3);
            const int cg = (lane & 7) ^ (r & 7);
            gld16(Ob + (long)(m0 + r) * 1024 + h * 64 + cg * 8, &As[r0 * 64]);
            gld16(WoT + (long)h * 65536 + (long)(n0 + r) * 64 + cg * 8, &Bs[r0 * 64]);
        }
        __syncthreads();
        #pragma unroll
        for (int ks = 0; ks < 2; ++ks) {
            bf16x8 af[4];
            #pragma unroll
            for (int ms = 0; ms < 4; ++ms)
                af[ms] = frag_swz(As, wm * 64 + ms * 16 + l15, ks * 4 + quad);
            #pragma unroll
            for (int ns = 0; ns < 4; ++ns) {
                const bf16x8 bfr = frag_swz(Bs, wn * 64 + ns * 16 + l15, ks * 4 + quad);
                #pragma unroll
                for (int ms = 0; ms < 4; ++ms)
                    acc[ms][ns] = MFMA16(af[ms], bfr, acc[ms][ns]);
            }
        }
    }

    // epilogue: bias_eff[n] = sum_h clamp(g_h)*bo[h][n]/16
    float gcl[16];
    #pragma unroll
    for (int hh = 0; hh < 16; ++hh)
        gcl[hh] = fminf(fmaxf(gate[hh], 0.f), 1.f) * (1.f / (float)NUM_HEADS);

    #pragma unroll
    for (int ns = 0; ns < 4; ++ns) {
        const int n = n0 + wn * 64 + ns * 16 + l15;
        float be = 0.f;
        #pragma unroll
        for (int hh = 0; hh < 16; ++hh) be += gcl[hh] * bo[hh * 1024 + n];
        #pragma unroll
        for (int ms = 0; ms < 4; ++ms) {
            const int m = m0 + wm * 64 + ms * 16 + quad * 4;
            #pragma unroll
            for (int r = 0; r < 4; ++r)
                out[(long)(m + r) * 1024 + n] = acc[ms][ns][r] + be;
        }
    }
}

// ---------------------------------------------------------------------------
extern "C" void kernel_launch(void* const* d_in, const int* in_sizes, int n_in,
                              void* d_out, int out_size, void* d_ws, size_t ws_size,
                              hipStream_t stream)
{
    const float* hs   = (const float*)d_in[0];
    const float* mask = (const float*)d_in[1];
    const float* Wq   = (const float*)d_in[2];
    const float* bq   = (const float*)d_in[3];
    const float* Wk   = (const float*)d_in[4];
    const float* bk   = (const float*)d_in[5];
    const float* Wv   = (const float*)d_in[6];
    const float* bv   = (const float*)d_in[7];
    const float* Wo   = (const float*)d_in[8];
    const float* bo   = (const float*)d_in[9];
    const float* gate = (const float*)d_in[10];
    float* out = (float*)d_out;

    char* ws = (char*)d_ws;
    const size_t MB = 1024 * 1024;
    short* hsb   = (short*)(ws);                 // 8 MB  (4096x1024)
    short* maskb = (short*)(ws + 8  * MB);       // 8 MB  (2048x2048)
    short* Wqt   = (short*)(ws + 16 * MB);       // 2 MB  (16x64x1024)
    short* Wkt   = (short*)(ws + 18 * MB);       // 2 MB
    short* Wvt   = (short*)(ws + 20 * MB);       // 2 MB
    short* WoT   = (short*)(ws + 22 * MB);       // 2 MB  (16x1024x64)
    short* Qb    = (short*)(ws + 24 * MB);       // 8 MB  [b,h,t,e]
    short* Kb    = (short*)(ws + 32 * MB);       // 8 MB  [b,h,t,e]
    short* Vtb   = (short*)(ws + 40 * MB);       // 8 MB  [b,h,e,t'] (kv-permuted)
    short* Ob    = (short*)(ws + 48 * MB);       // 8 MB  [b,t,h*64+e]
    float* denomsum = (float*)(ws + 56 * MB);    // 16 floats

    hipMemsetAsync(denomsum, 0, NUM_HEADS * sizeof(float), stream);

    cvt_in_kernel<<<dim3(4096, 2), 256, 0, stream>>>(hs, mask, hsb, maskb);
    transpose_w_kernel<<<dim3(64, 16, 4), 256, 0, stream>>>(
        Wq, Wk, Wv, Wo, Wqt, Wkt, Wvt, WoT);
    qkv_mfma_kernel<<<dim3(32, 16), 256, 0, stream>>>(
        hsb, Wqt, Wkt, Wvt, bq, bk, bv, Qb, Kb, Vtb);
    attn_mfma_kernel<<<dim3(16, 16, 2), 256, 0, stream>>>(
        Qb, Kb, Vtb, maskb, Ob, denomsum);
    scale_o_kernel<<<4096, 256, 0, stream>>>(Ob, denomsum, gate);
    oproj_mfma_kernel<<<dim3(32, 8), 256, 0, stream>>>(
        Ob, WoT, bo, gate, out);
}

// Round 4
// 281.693 us; speedup vs baseline: 4.7280x; 1.0485x over previous
//
#include <hip/hip_runtime.h>
#include <hip/hip_bf16.h>
#include <math.h>

#define EMBED_DIM 1024
#define NUM_HEADS 16
#define HEAD_DIM  64
#define B_SZ      2
#define T_SZ      2048
#define BT        (B_SZ * T_SZ)      // 4096
#define LOG2E     1.44269504088896340736f
#define QSCALE    (0.125f * LOG2E)   // softmax scale folded with log2e into Q

typedef short bf16x8 __attribute__((ext_vector_type(8)));   // 8 bf16 in 4 VGPRs
typedef float f32x4  __attribute__((ext_vector_type(4)));

#define MFMA16(a, b, c) __builtin_amdgcn_mfma_f32_16x16x32_bf16((a), (b), (c), 0, 0, 0)

// float -> bf16 (RNE), bf16 -> float
__device__ inline short f2bf(float f) {
    unsigned u = __builtin_bit_cast(unsigned, f);
    u = (u + 0x7fffu + ((u >> 16) & 1u)) >> 16;
    return (short)u;
}
__device__ inline float bf2f(short s) {
    unsigned u = ((unsigned)(unsigned short)s) << 16;
    return __builtin_bit_cast(float, u);
}
// pack two f32 -> bf16x2 in one u32 (packed cvt when HW has it)
__device__ inline unsigned pk2(float a, float b) {
#if __has_builtin(__builtin_amdgcn_cvt_pk_bf16_f32)
    typedef __bf16 bf2_t __attribute__((ext_vector_type(2)));
    bf2_t t = __builtin_amdgcn_cvt_pk_bf16_f32(a, b);
    return __builtin_bit_cast(unsigned, t);
#else
    return (unsigned)(unsigned short)f2bf(a) | ((unsigned)(unsigned short)f2bf(b) << 16);
#endif
}

// async global->LDS, 16B per lane; lds base must be wave-uniform (lane*16 auto)
__device__ inline void gld16(const short* g, short* lds) {
    __builtin_amdgcn_global_load_lds(
        (const __attribute__((address_space(1))) void*)g,
        (__attribute__((address_space(3))) void*)lds, 16, 0, 0);
}

// swizzled frag read from a [rows][64] bf16 tile staged with chunk c at c^(r&7)
__device__ inline bf16x8 frag_swz(const short* tile, int R, int C) {
    return *(const bf16x8*)(tile + R * 64 + ((C ^ (R & 7)) << 3));
}

__device__ inline float red_add64(float v) {
    v += __shfl_xor(v, 1); v += __shfl_xor(v, 2); v += __shfl_xor(v, 4);
    v += __shfl_xor(v, 8); v += __shfl_xor(v, 16); v += __shfl_xor(v, 32);
    return v;
}

// ---------------------------------------------------------------------------
// K0: convert hs -> bf16.  grid 4096 x 256
// ---------------------------------------------------------------------------
__global__ __launch_bounds__(256) void cvt_in_kernel(
    const float* __restrict__ hs, short* __restrict__ hsb)
{
    const long i = ((long)blockIdx.x * 256 + threadIdx.x) * 4;
    const float4 v = *(const float4*)(hs + i);
    ushort4 o; o.x = f2bf(v.x); o.y = f2bf(v.y); o.z = f2bf(v.z); o.w = f2bf(v.w);
    *(ushort4*)(hsb + i) = o;
}

// ---------------------------------------------------------------------------
// K1: per-head weight transposes, fp32 -> bf16.
// arr 0..2: Wq/Wk/Wv [1024][64] -> [64][1024]; arr 3: Wo [64][1024] -> [1024][64]
// grid (64, 16, 4) x 256
// ---------------------------------------------------------------------------
__global__ __launch_bounds__(256) void transpose_w_kernel(
    const float* __restrict__ Wq, const float* __restrict__ Wk,
    const float* __restrict__ Wv, const float* __restrict__ Wo,
    short* __restrict__ Wqt, short* __restrict__ Wkt,
    short* __restrict__ Wvt, short* __restrict__ WoT)
{
    const int arr = blockIdx.z, h = blockIdx.y;
    const float* src; short* dst; int R, C;
    if (arr == 0)      { src = Wq; dst = Wqt; R = 1024; C = 64; }
    else if (arr == 1) { src = Wk; dst = Wkt; R = 1024; C = 64; }
    else if (arr == 2) { src = Wv; dst = Wvt; R = 1024; C = 64; }
    else               { src = Wo; dst = WoT; R = 64;   C = 1024; }
    src += (long)h * 65536; dst += (long)h * 65536;

    const int ct = C / 32;
    const int tr = blockIdx.x / ct, tc = blockIdx.x % ct;
    __shared__ float tile[32][33];
    const int tx = threadIdx.x & 31, ty = threadIdx.x >> 5;   // 32 x 8
    #pragma unroll
    for (int i = 0; i < 4; ++i) {
        const int r = ty + 8 * i;
        tile[r][tx] = src[(long)(tr * 32 + r) * C + tc * 32 + tx];
    }
    __syncthreads();
    #pragma unroll
    for (int i = 0; i < 4; ++i) {
        const int r = ty + 8 * i;
        dst[(long)(tc * 32 + r) * R + tr * 32 + tx] = f2bf(tile[tx][r]);
    }
}

// ---------------------------------------------------------------------------
// K2: fused QKV projection, MFMA.  grid (32, 16) x 256 (4 waves, 2x2).
// BM=128, BN=192 (q|k|v for one head), BK=64.  Wave tile 64x96.
// Q written *QSCALE, layout [b,h,t,e]; K same; V written transposed [b,h,e,t']
// with t' = kv-permutation within each 64-tile so attention's PV A-frags are
// contiguous b128 reads: t' = (t&~63)|(t&35)|((t&12)<<1)|((t&16)>>2).
// ---------------------------------------------------------------------------
__global__ __launch_bounds__(256) void qkv_mfma_kernel(
    const short* __restrict__ hsb,
    const short* __restrict__ Wqt, const short* __restrict__ Wkt,
    const short* __restrict__ Wvt,
    const float* __restrict__ bq, const float* __restrict__ bk,
    const float* __restrict__ bv,
    short* __restrict__ Qb, short* __restrict__ Kb, short* __restrict__ Vtb)
{
    const int m0 = blockIdx.x * 128;
    const int h  = blockIdx.y;
    __shared__ short As[128 * 64];
    __shared__ short Bs[3][64 * 64];

    const int tid = threadIdx.x, lane = tid & 63, w = tid >> 6;
    const int wm = w & 1, wn = w >> 1;
    const int quad = lane >> 4, l15 = lane & 15;

    const short* Wt0 = Wqt + (long)h * 65536;
    const short* Wt1 = Wkt + (long)h * 65536;
    const short* Wt2 = Wvt + (long)h * 65536;

    f32x4 acc[4][6] = {};

    for (int k0 = 0; k0 < 1024; k0 += 64) {
        __syncthreads();
        // stage A (128x64), 4 instrs/wave
        #pragma unroll
        for (int t = 0; t < 4; ++t) {
            const int r0 = w * 32 + t * 8;
            const int r  = r0 + (lane >> 3);
            const int cg = (lane & 7) ^ (r & 7);
            gld16(hsb + (long)(m0 + r) * 1024 + k0 + cg * 8, &As[r0 * 64]);
        }
        // stage B (3 x 64x64), 6 instrs/wave
        #pragma unroll
        for (int t = 0; t < 2; ++t) {
            const int r0 = w * 16 + t * 8;
            const int r  = r0 + (lane >> 3);
            const int cg = (lane & 7) ^ (r & 7);
            gld16(Wt0 + (long)r * 1024 + k0 + cg * 8, &Bs[0][r0 * 64]);
            gld16(Wt1 + (long)r * 1024 + k0 + cg * 8, &Bs[1][r0 * 64]);
            gld16(Wt2 + (long)r * 1024 + k0 + cg * 8, &Bs[2][r0 * 64]);
        }
        __syncthreads();
        #pragma unroll
        for (int ks = 0; ks < 2; ++ks) {
            bf16x8 af[4];
            #pragma unroll
            for (int ms = 0; ms < 4; ++ms)
                af[ms] = frag_swz(As, wm * 64 + ms * 16 + l15, ks * 4 + quad);
            #pragma unroll
            for (int ns = 0; ns < 6; ++ns) {
                const int gn  = wn * 6 + ns;
                const int arr = gn >> 2;
                const bf16x8 bfr = frag_swz(&Bs[arr][0], (gn & 3) * 16 + l15, ks * 4 + quad);
                #pragma unroll
                for (int ms = 0; ms < 4; ++ms)
                    acc[ms][ns] = MFMA16(af[ms], bfr, acc[ms][ns]);
            }
        }
    }

    // epilogue
    #pragma unroll
    for (int ns = 0; ns < 6; ++ns) {
        const int gn  = wn * 6 + ns;
        const int arr = gn >> 2;
        const int e   = (gn & 3) * 16 + l15;
        const float bias = (arr == 0 ? bq : arr == 1 ? bk : bv)[h * 64 + e];
        #pragma unroll
        for (int ms = 0; ms < 4; ++ms) {
            const int mbase = m0 + wm * 64 + ms * 16 + quad * 4;
            const int bb = mbase >> 11, t0 = mbase & 2047;
            if (arr == 2) {
                const int tp = (t0 & ~63) | (t0 & 35) | ((t0 & 12) << 1) | ((t0 & 16) >> 2);
                ushort4 pk;
                pk.x = (unsigned short)f2bf(acc[ms][ns][0] + bias);
                pk.y = (unsigned short)f2bf(acc[ms][ns][1] + bias);
                pk.z = (unsigned short)f2bf(acc[ms][ns][2] + bias);
                pk.w = (unsigned short)f2bf(acc[ms][ns][3] + bias);
                *(ushort4*)&Vtb[((long)(bb * 16 + h) * 64 + e) * 2048 + tp] = pk;
            } else {
                #pragma unroll
                for (int r = 0; r < 4; ++r) {
                    const float v = acc[ms][ns][r] + bias;
                    const long off = ((long)(bb * 16 + h) * 2048 + (t0 + r)) * 64 + e;
                    if (arr == 0) Qb[off] = f2bf(v * QSCALE);
                    else          Kb[off] = f2bf(v);
                }
            }
        }
    }
}

// ---------------------------------------------------------------------------
// K3: flash attention, transposed-S formulation.  grid (32, 16, 2) x 256.
// BQ=64 (16 q-rows per wave) -> 1024 blocks = 4 blocks/CU for VALU-latency
// hiding.  S^T = K·Q^T (rows lane-local softmax).  P^T stays in registers as
// the PV B-operand via the k<->kv bijection (V pre-permuted at QKV time).
// Mask loaded fp32 and applied via FMA with LOG2E.
// ---------------------------------------------------------------------------
__global__ __launch_bounds__(256) void attn_mfma_kernel(
    const short* __restrict__ Qb, const short* __restrict__ Kb,
    const short* __restrict__ Vtb, const float* __restrict__ maskf,
    short* __restrict__ Ob, float* __restrict__ denomsum)
{
    const int q0 = blockIdx.x * 64;
    const int h  = blockIdx.y, b = blockIdx.z;
    const long bh = ((long)b * 16 + h) * (long)T_SZ * 64;

    __shared__ short Ks[64 * 64];
    __shared__ short Vs[64 * 64];
    __shared__ float wred[4];

    const int tid = threadIdx.x, lane = tid & 63, w = tid >> 6;
    const int quad = lane >> 4, l15 = lane & 15;
    const int qrow = q0 + w * 16 + l15;       // this lane's q row

    // Q fragments (B-operand of K·Q^T): lane holds q-row = l15 slot
    bf16x8 qf[2];
    #pragma unroll
    for (int ks = 0; ks < 2; ++ks)
        qf[ks] = *(const bf16x8*)(Qb + bh + (long)qrow * 64 + ks * 32 + quad * 8);

    f32x4 o[4] = {};            // O^T: row e = eb*16 + quad*4 + r, col q = l15
    float m2 = -3.0e38f;        // per-lane running max (log2 domain)
    float lp = 0.f;             // per-lane partial row sum (this quad's kv)

    const short* Kg = Kb + bh;
    const short* Vg = Vtb + bh;   // [64 e][2048 t'] (kv-permuted within 64-tiles)
    const float* mrow = maskf + (long)qrow * 2048 + quad * 4;

    for (int kt = 0; kt < 32; ++kt) {
        const int kv0 = kt * 64;
        __syncthreads();
        #pragma unroll
        for (int t = 0; t < 2; ++t) {
            const int r0 = w * 16 + t * 8;
            const int r  = r0 + (lane >> 3);
            const int cg = (lane & 7) ^ (r & 7);
            gld16(Kg + (long)(kv0 + r) * 64 + cg * 8, &Ks[r0 * 64]);
            gld16(Vg + (long)r * 2048 + kv0 + cg * 8, &Vs[r0 * 64]);
        }
        __syncthreads();

        // S^T = K Q^T : s[kb] holds kv = kv0+kb*16+quad*4+r, q = l15
        f32x4 s[4] = {};
        #pragma unroll
        for (int ks = 0; ks < 2; ++ks)
            #pragma unroll
            for (int kb = 0; kb < 4; ++kb) {
                const bf16x8 kf = frag_swz(Ks, kb * 16 + l15, ks * 4 + quad);
                s[kb] = MFMA16(kf, qf[ks], s[kb]);
            }

        // + mask*log2e (fp32 mask, fma)
        #pragma unroll
        for (int kb = 0; kb < 4; ++kb) {
            const float4 mv = *(const float4*)(mrow + kv0 + kb * 16);
            s[kb][0] = fmaf(mv.x, LOG2E, s[kb][0]);
            s[kb][1] = fmaf(mv.y, LOG2E, s[kb][1]);
            s[kb][2] = fmaf(mv.z, LOG2E, s[kb][2]);
            s[kb][3] = fmaf(mv.w, LOG2E, s[kb][3]);
        }

        // online softmax (base-2), rows lane-local
        float mx = fmaxf(fmaxf(s[0][0], s[0][1]), fmaxf(s[0][2], s[0][3]));
        #pragma unroll
        for (int kb = 1; kb < 4; ++kb)
            mx = fmaxf(mx, fmaxf(fmaxf(s[kb][0], s[kb][1]), fmaxf(s[kb][2], s[kb][3])));
        mx = fmaxf(mx, __shfl_xor(mx, 16));
        mx = fmaxf(mx, __shfl_xor(mx, 32));
        const float mn = fmaxf(m2, mx);
        const float al = exp2f(m2 - mn);
        m2 = mn;
        #pragma unroll
        for (int eb = 0; eb < 4; ++eb) o[eb] *= al;
        float rs = 0.f;
        unsigned w0[4], w1[4];
        #pragma unroll
        for (int kb = 0; kb < 4; ++kb) {
            const float p0 = exp2f(s[kb][0] - mn);
            const float p1 = exp2f(s[kb][1] - mn);
            const float p2 = exp2f(s[kb][2] - mn);
            const float p3 = exp2f(s[kb][3] - mn);
            rs += (p0 + p1) + (p2 + p3);
            w0[kb] = pk2(p0, p1);
            w1[kb] = pk2(p2, p3);
        }
        lp = lp * al + rs;
        bf16x8 pb[2];
        #pragma unroll
        for (int kbp = 0; kbp < 2; ++kbp) {
            const uint4 u = {w0[2 * kbp], w1[2 * kbp], w0[2 * kbp + 1], w1[2 * kbp + 1]};
            pb[kbp] = __builtin_bit_cast(bf16x8, u);
        }

        // O^T += V^T P^T  (K=32 MFMA, custom k<->kv bijection; V pre-permuted)
        #pragma unroll
        for (int kbp = 0; kbp < 2; ++kbp)
            #pragma unroll
            for (int eb = 0; eb < 4; ++eb) {
                const bf16x8 va = frag_swz(Vs, eb * 16 + l15, kbp * 4 + quad);
                o[eb] = MFMA16(va, pb[kbp], o[eb]);
            }
    }

    // epilogue: finish row sums, normalize, write O^T, row-norm reduction
    float lf = lp;
    lf += __shfl_xor(lf, 16);
    lf += __shfl_xor(lf, 32);
    const float inv = 1.f / lf;
    float ss = 0.f;
    #pragma unroll
    for (int eb = 0; eb < 4; ++eb) {
        o[eb] *= inv;
        #pragma unroll
        for (int r = 0; r < 4; ++r) ss += o[eb][r] * o[eb][r];
    }
    ss += __shfl_xor(ss, 16);
    ss += __shfl_xor(ss, 32);
    const float tot = sqrtf(ss);

    #pragma unroll
    for (int eb = 0; eb < 4; ++eb) {
        uint2 pk;
        pk.x = pk2(o[eb][0], o[eb][1]);
        pk.y = pk2(o[eb][2], o[eb][3]);
        *(uint2*)&Ob[((long)(b * 2048 + qrow)) * 1024 + h * 64 + eb * 16 + quad * 4] = pk;
    }
    // each row's norm appears in 4 lanes (quads): sum all, divide by 4
    const float wsum = red_add64(tot) * 0.25f;
    if (lane == 0) wred[w] = wsum;
    __syncthreads();
    if (tid == 0)
        atomicAdd(&denomsum[h], wred[0] + wred[1] + wred[2] + wred[3]);
}

// ---------------------------------------------------------------------------
// K4: scale WoT rows (per head) by g_h / (denom_h * H), in place.
// WoT regenerated by transpose_w every call -> in-place is replay-safe.
// grid 1024 x 256 (16*1024*64 = 1,048,576 elements, 4 per thread)
// ---------------------------------------------------------------------------
__global__ __launch_bounds__(256) void scale_w_kernel(
    short* __restrict__ WoT, const float* __restrict__ denomsum,
    const float* __restrict__ gate)
{
    __shared__ float sh[16];
    if (threadIdx.x < 16) {
        const float g  = fminf(fmaxf(gate[threadIdx.x], 0.f), 1.f);
        const float dn = fmaxf(denomsum[threadIdx.x] * (1.f / (float)BT), 1e-5f);
        sh[threadIdx.x] = g / (dn * (float)NUM_HEADS);
    }
    __syncthreads();
    const long i = ((long)blockIdx.x * 256 + threadIdx.x) * 4;
    const float sc = sh[(int)(i >> 16)];
    ushort4 v = *(ushort4*)(WoT + i);
    v.x = (unsigned short)f2bf(bf2f((short)v.x) * sc);
    v.y = (unsigned short)f2bf(bf2f((short)v.y) * sc);
    v.z = (unsigned short)f2bf(bf2f((short)v.z) * sc);
    v.w = (unsigned short)f2bf(bf2f((short)v.w) * sc);
    *(ushort4*)(WoT + i) = v;
}

// ---------------------------------------------------------------------------
// K5: output projection, MFMA.  grid (32, 8) x 256 (2x2 waves, wave 64x64).
// BM=128, BN=128, BK=64 (= one head per k-iter).  Bias folded in epilogue.
// ---------------------------------------------------------------------------
__global__ __launch_bounds__(256) void oproj_mfma_kernel(
    const short* __restrict__ Ob,    // [4096][1024] raw attention out
    const short* __restrict__ WoT,   // [16][1024][64], pre-scaled by s_h
    const float* __restrict__ bo,    // [16][1024]
    const float* __restrict__ gate,
    float* __restrict__ out)         // [4096][1024]
{
    const int m0 = blockIdx.x * 128;
    const int n0 = blockIdx.y * 128;
    __shared__ short As[128 * 64];
    __shared__ short Bs[128 * 64];

    const int tid = threadIdx.x, lane = tid & 63, w = tid >> 6;
    const int wm = w & 1, wn = w >> 1;
    const int quad = lane >> 4, l15 = lane & 15;

    f32x4 acc[4][4] = {};

    for (int h = 0; h < 16; ++h) {
        __syncthreads();
        #pragma unroll
        for (int t = 0; t < 4; ++t) {
            const int r0 = w * 32 + t * 8;
            const int r  = r0 + (lane >> 3);
            const int cg = (lane & 7) ^ (r & 7);
            gld16(Ob + (long)(m0 + r) * 1024 + h * 64 + cg * 8, &As[r0 * 64]);
            gld16(WoT + (long)h * 65536 + (long)(n0 + r) * 64 + cg * 8, &Bs[r0 * 64]);
        }
        __syncthreads();
        #pragma unroll
        for (int ks = 0; ks < 2; ++ks) {
            bf16x8 af[4];
            #pragma unroll
            for (int ms = 0; ms < 4; ++ms)
                af[ms] = frag_swz(As, wm * 64 + ms * 16 + l15, ks * 4 + quad);
            #pragma unroll
            for (int ns = 0; ns < 4; ++ns) {
                const bf16x8 bfr = frag_swz(Bs, wn * 64 + ns * 16 + l15, ks * 4 + quad);
                #pragma unroll
                for (int ms = 0; ms < 4; ++ms)
                    acc[ms][ns] = MFMA16(af[ms], bfr, acc[ms][ns]);
            }
        }
    }

    // epilogue: bias_eff[n] = sum_h clamp(g_h)*bo[h][n]/16
    float gcl[16];
    #pragma unroll
    for (int hh = 0; hh < 16; ++hh)
        gcl[hh] = fminf(fmaxf(gate[hh], 0.f), 1.f) * (1.f / (float)NUM_HEADS);

    #pragma unroll
    for (int ns = 0; ns < 4; ++ns) {
        const int n = n0 + wn * 64 + ns * 16 + l15;
        float be = 0.f;
        #pragma unroll
        for (int hh = 0; hh < 16; ++hh) be += gcl[hh] * bo[hh * 1024 + n];
        #pragma unroll
        for (int ms = 0; ms < 4; ++ms) {
            const int m = m0 + wm * 64 + ms * 16 + quad * 4;
            #pragma unroll
            for (int r = 0; r < 4; ++r)
                out[(long)(m + r) * 1024 + n] = acc[ms][ns][r] + be;
        }
    }
}

// ---------------------------------------------------------------------------
extern "C" void kernel_launch(void* const* d_in, const int* in_sizes, int n_in,
                              void* d_out, int out_size, void* d_ws, size_t ws_size,
                              hipStream_t stream)
{
    const float* hs   = (const float*)d_in[0];
    const float* mask = (const float*)d_in[1];
    const float* Wq   = (const float*)d_in[2];
    const float* bq   = (const float*)d_in[3];
    const float* Wk   = (const float*)d_in[4];
    const float* bk   = (const float*)d_in[5];
    const float* Wv   = (const float*)d_in[6];
    const float* bv   = (const float*)d_in[7];
    const float* Wo   = (const float*)d_in[8];
    const float* bo   = (const float*)d_in[9];
    const float* gate = (const float*)d_in[10];
    float* out = (float*)d_out;

    char* ws = (char*)d_ws;
    const size_t MB = 1024 * 1024;
    short* hsb   = (short*)(ws);                 // 8 MB  (4096x1024)
    short* Wqt   = (short*)(ws + 8  * MB);       // 2 MB  (16x64x1024)
    short* Wkt   = (short*)(ws + 10 * MB);       // 2 MB
    short* Wvt   = (short*)(ws + 12 * MB);       // 2 MB
    short* WoT   = (short*)(ws + 14 * MB);       // 2 MB  (16x1024x64)
    short* Qb    = (short*)(ws + 16 * MB);       // 8 MB  [b,h,t,e]
    short* Kb    = (short*)(ws + 24 * MB);       // 8 MB  [b,h,t,e]
    short* Vtb   = (short*)(ws + 32 * MB);       // 8 MB  [b,h,e,t'] (kv-permuted)
    short* Ob    = (short*)(ws + 40 * MB);       // 8 MB  [b,t,h*64+e]
    float* denomsum = (float*)(ws + 48 * MB);    // 16 floats

    hipMemsetAsync(denomsum, 0, NUM_HEADS * sizeof(float), stream);

    cvt_in_kernel<<<4096, 256, 0, stream>>>(hs, hsb);
    transpose_w_kernel<<<dim3(64, 16, 4), 256, 0, stream>>>(
        Wq, Wk, Wv, Wo, Wqt, Wkt, Wvt, WoT);
    qkv_mfma_kernel<<<dim3(32, 16), 256, 0, stream>>>(
        hsb, Wqt, Wkt, Wvt, bq, bk, bv, Qb, Kb, Vtb);
    attn_mfma_kernel<<<dim3(32, 16, 2), 256, 0, stream>>>(
        Qb, Kb, Vtb, mask, Ob, denomsum);
    scale_w_kernel<<<1024, 256, 0, stream>>>(WoT, denomsum, gate);
    oproj_mfma_kernel<<<dim3(32, 8), 256, 0, stream>>>(
        Ob, WoT, bo, gate, out);
}

// Round 6
// 280.532 us; speedup vs baseline: 4.7476x; 1.0041x over previous
//
#include <hip/hip_runtime.h>
#include <hip/hip_bf16.h>
#include <math.h>

#define EMBED_DIM 1024
#define NUM_HEADS 16
#define HEAD_DIM  64
#define B_SZ      2
#define T_SZ      2048
#define BT        (B_SZ * T_SZ)      // 4096
#define LOG2E     1.44269504088896340736f
#define QSCALE    (0.125f * LOG2E)   // softmax scale folded with log2e into Q

typedef short bf16x8 __attribute__((ext_vector_type(8)));   // 8 bf16 in 4 VGPRs
typedef float f32x4  __attribute__((ext_vector_type(4)));

#define MFMA16(a, b, c) __builtin_amdgcn_mfma_f32_16x16x32_bf16((a), (b), (c), 0, 0, 0)

// float -> bf16 (RNE), bf16 -> float
__device__ inline short f2bf(float f) {
    unsigned u = __builtin_bit_cast(unsigned, f);
    u = (u + 0x7fffu + ((u >> 16) & 1u)) >> 16;
    return (short)u;
}
__device__ inline float bf2f(short s) {
    unsigned u = ((unsigned)(unsigned short)s) << 16;
    return __builtin_bit_cast(float, u);
}
// pack two f32 -> bf16x2 in one u32 (packed cvt when HW has it)
__device__ inline unsigned pk2(float a, float b) {
#if __has_builtin(__builtin_amdgcn_cvt_pk_bf16_f32)
    typedef __bf16 bf2_t __attribute__((ext_vector_type(2)));
    bf2_t t = __builtin_amdgcn_cvt_pk_bf16_f32(a, b);
    return __builtin_bit_cast(unsigned, t);
#else
    return (unsigned)(unsigned short)f2bf(a) | ((unsigned)(unsigned short)f2bf(b) << 16);
#endif
}

// async global->LDS, 16B per lane; lds base must be wave-uniform (lane*16 auto)
__device__ inline void gld16(const short* g, short* lds) {
    __builtin_amdgcn_global_load_lds(
        (const __attribute__((address_space(1))) void*)g,
        (__attribute__((address_space(3))) void*)lds, 16, 0, 0);
}

// swizzled frag read from a [rows][64] bf16 tile staged with chunk c at c^(r&7)
__device__ inline bf16x8 frag_swz(const short* tile, int R, int C) {
    return *(const bf16x8*)(tile + R * 64 + ((C ^ (R & 7)) << 3));
}

__device__ inline float red_add64(float v) {
    v += __shfl_xor(v, 1); v += __shfl_xor(v, 2); v += __shfl_xor(v, 4);
    v += __shfl_xor(v, 8); v += __shfl_xor(v, 16); v += __shfl_xor(v, 32);
    return v;
}

// ---------------------------------------------------------------------------
// K0: convert hs -> bf16.  grid 4096 x 256
// ---------------------------------------------------------------------------
__global__ __launch_bounds__(256) void cvt_in_kernel(
    const float* __restrict__ hs, short* __restrict__ hsb)
{
    const long i = ((long)blockIdx.x * 256 + threadIdx.x) * 4;
    const float4 v = *(const float4*)(hs + i);
    ushort4 o; o.x = f2bf(v.x); o.y = f2bf(v.y); o.z = f2bf(v.z); o.w = f2bf(v.w);
    *(ushort4*)(hsb + i) = o;
}

// ---------------------------------------------------------------------------
// K1: per-head weight transposes, fp32 -> bf16.
// arr 0..2: Wq/Wk/Wv [1024][64] -> [64][1024]; arr 3: Wo [64][1024] -> [1024][64]
// grid (64, 16, 4) x 256
// ---------------------------------------------------------------------------
__global__ __launch_bounds__(256) void transpose_w_kernel(
    const float* __restrict__ Wq, const float* __restrict__ Wk,
    const float* __restrict__ Wv, const float* __restrict__ Wo,
    short* __restrict__ Wqt, short* __restrict__ Wkt,
    short* __restrict__ Wvt, short* __restrict__ WoT)
{
    const int arr = blockIdx.z, h = blockIdx.y;
    const float* src; short* dst; int R, C;
    if (arr == 0)      { src = Wq; dst = Wqt; R = 1024; C = 64; }
    else if (arr == 1) { src = Wk; dst = Wkt; R = 1024; C = 64; }
    else if (arr == 2) { src = Wv; dst = Wvt; R = 1024; C = 64; }
    else               { src = Wo; dst = WoT; R = 64;   C = 1024; }
    src += (long)h * 65536; dst += (long)h * 65536;

    const int ct = C / 32;
    const int tr = blockIdx.x / ct, tc = blockIdx.x % ct;
    __shared__ float tile[32][33];
    const int tx = threadIdx.x & 31, ty = threadIdx.x >> 5;   // 32 x 8
    #pragma unroll
    for (int i = 0; i < 4; ++i) {
        const int r = ty + 8 * i;
        tile[r][tx] = src[(long)(tr * 32 + r) * C + tc * 32 + tx];
    }
    __syncthreads();
    #pragma unroll
    for (int i = 0; i < 4; ++i) {
        const int r = ty + 8 * i;
        dst[(long)(tc * 32 + r) * R + tr * 32 + tx] = f2bf(tile[tx][r]);
    }
}

// ---------------------------------------------------------------------------
// K2: fused QKV projection as ONE flat GEMM: [4096,1024] x Wt^T, Wt = [3072,1024]
// (rows n = type*1024 + h*64 + e; Wqt/Wkt/Wvt are contiguous in ws).
// grid (32, 24) x 256 (2x2 waves, 64x64/wave), BM=BN=128, BK=64.
// Epilogue decodes (type,h,e) from n: Q *QSCALE -> [b,h,t,e]; K -> [b,h,t,e];
// V -> transposed [b,h,e,t'] with the kv-permutation
// t' = (t&~63)|(t&35)|((t&12)<<1)|((t&16)>>2).
// ---------------------------------------------------------------------------
__global__ __launch_bounds__(256) void qkv_mfma_kernel(
    const short* __restrict__ hsb,
    const short* __restrict__ Wt,      // [3072][1024]
    const float* __restrict__ bq, const float* __restrict__ bk,
    const float* __restrict__ bv,
    short* __restrict__ Qb, short* __restrict__ Kb, short* __restrict__ Vtb)
{
    const int m0 = blockIdx.x * 128;
    const int n0 = blockIdx.y * 128;
    __shared__ short As[128 * 64];
    __shared__ short Bs[128 * 64];

    const int tid = threadIdx.x, lane = tid & 63, w = tid >> 6;
    const int wm = w & 1, wn = w >> 1;
    const int quad = lane >> 4, l15 = lane & 15;

    f32x4 acc[4][4] = {};

    for (int k0 = 0; k0 < 1024; k0 += 64) {
        __syncthreads();
        #pragma unroll
        for (int t = 0; t < 4; ++t) {
            const int r0 = w * 32 + t * 8;
            const int r  = r0 + (lane >> 3);
            const int cg = (lane & 7) ^ (r & 7);
            gld16(hsb + (long)(m0 + r) * 1024 + k0 + cg * 8, &As[r0 * 64]);
            gld16(Wt  + (long)(n0 + r) * 1024 + k0 + cg * 8, &Bs[r0 * 64]);
        }
        __syncthreads();
        #pragma unroll
        for (int ks = 0; ks < 2; ++ks) {
            bf16x8 af[4];
            #pragma unroll
            for (int ms = 0; ms < 4; ++ms)
                af[ms] = frag_swz(As, wm * 64 + ms * 16 + l15, ks * 4 + quad);
            #pragma unroll
            for (int ns = 0; ns < 4; ++ns) {
                const bf16x8 bfr = frag_swz(Bs, wn * 64 + ns * 16 + l15, ks * 4 + quad);
                #pragma unroll
                for (int ms = 0; ms < 4; ++ms)
                    acc[ms][ns] = MFMA16(af[ms], bfr, acc[ms][ns]);
            }
        }
    }

    // epilogue: n -> (type, h, e)
    #pragma unroll
    for (int ns = 0; ns < 4; ++ns) {
        const int n    = n0 + wn * 64 + ns * 16 + l15;
        const int type = n >> 10;          // wave-uniform
        const int h    = (n >> 6) & 15;    // wave-uniform
        const int e    = n & 63;
        const float bias = (type == 0 ? bq : type == 1 ? bk : bv)[h * 64 + e];
        #pragma unroll
        for (int ms = 0; ms < 4; ++ms) {
            const int mbase = m0 + wm * 64 + ms * 16 + quad * 4;
            const int bb = mbase >> 11, t0 = mbase & 2047;
            if (type == 2) {
                const int tp = (t0 & ~63) | (t0 & 35) | ((t0 & 12) << 1) | ((t0 & 16) >> 2);
                ushort4 pk;
                pk.x = (unsigned short)f2bf(acc[ms][ns][0] + bias);
                pk.y = (unsigned short)f2bf(acc[ms][ns][1] + bias);
                pk.z = (unsigned short)f2bf(acc[ms][ns][2] + bias);
                pk.w = (unsigned short)f2bf(acc[ms][ns][3] + bias);
                *(ushort4*)&Vtb[((long)(bb * 16 + h) * 64 + e) * 2048 + tp] = pk;
            } else {
                #pragma unroll
                for (int r = 0; r < 4; ++r) {
                    const float v = acc[ms][ns][r] + bias;
                    const long off = ((long)(bb * 16 + h) * 2048 + (t0 + r)) * 64 + e;
                    if (type == 0) Qb[off] = f2bf(v * QSCALE);
                    else           Kb[off] = f2bf(v);
                }
            }
        }
    }
}

// ---------------------------------------------------------------------------
// K3: flash attention, transposed-S, double-buffered K/V with single-barrier
// prefetch: at each kt the vmcnt drain waits on loads issued a full compute
// phase earlier (hidden latency).  grid (32, 16, 2) x 256, BQ=64.
// ---------------------------------------------------------------------------
__global__ __launch_bounds__(256) void attn_mfma_kernel(
    const short* __restrict__ Qb, const short* __restrict__ Kb,
    const short* __restrict__ Vtb, const float* __restrict__ maskf,
    short* __restrict__ Ob, float* __restrict__ denomsum)
{
    const int q0 = blockIdx.x * 64;
    const int h  = blockIdx.y, b = blockIdx.z;
    const long bh = ((long)b * 16 + h) * (long)T_SZ * 64;

    __shared__ short Ks[2][64 * 64];
    __shared__ short Vs[2][64 * 64];
    __shared__ float wred[4];

    const int tid = threadIdx.x, lane = tid & 63, w = tid >> 6;
    const int quad = lane >> 4, l15 = lane & 15;
    const int qrow = q0 + w * 16 + l15;       // this lane's q row

    const short* Kg = Kb + bh;
    const short* Vg = Vtb + bh;   // [64 e][2048 t'] (kv-permuted within 64-tiles)

    const int sr0 = w * 16;                   // this wave's staging rows
    const int sr  = lane >> 3;
    const int scg = (lane & 7);

    // stage kt's K/V tiles into buffer `buf`
    auto stage = [&](int kt, int buf) {
        const int kv0 = kt * 64;
        #pragma unroll
        for (int t = 0; t < 2; ++t) {
            const int r0 = sr0 + t * 8;
            const int r  = r0 + sr;
            const int cg = scg ^ (r & 7);
            gld16(Kg + (long)(kv0 + r) * 64 + cg * 8, &Ks[buf][r0 * 64]);
            gld16(Vg + (long)r * 2048 + kv0 + cg * 8, &Vs[buf][r0 * 64]);
        }
    };

    // Q fragments (B-operand of K·Q^T): lane holds q-row = l15 slot
    bf16x8 qf[2];
    #pragma unroll
    for (int ks = 0; ks < 2; ++ks)
        qf[ks] = *(const bf16x8*)(Qb + bh + (long)qrow * 64 + ks * 32 + quad * 8);

    f32x4 o[4] = {};            // O^T: row e = eb*16 + quad*4 + r, col q = l15
    float m2 = -3.0e38f;        // per-lane running max (log2 domain)
    float lp = 0.f;             // per-lane partial row sum (this quad's kv)

    const float* mrow = maskf + (long)qrow * 2048 + quad * 4;

    stage(0, 0);

    for (int kt = 0; kt < 32; ++kt) {
        const int cur = kt & 1;
        const int kv0 = kt * 64;
        __syncthreads();                 // buf[cur] ready (loads issued kt-1) & visible
        if (kt < 31) stage(kt + 1, cur ^ 1);

        // S^T = K Q^T : s[kb] holds kv = kv0+kb*16+quad*4+r, q = l15
        f32x4 s[4] = {};
        #pragma unroll
        for (int ks = 0; ks < 2; ++ks)
            #pragma unroll
            for (int kb = 0; kb < 4; ++kb) {
                const bf16x8 kf = frag_swz(&Ks[cur][0], kb * 16 + l15, ks * 4 + quad);
                s[kb] = MFMA16(kf, qf[ks], s[kb]);
            }

        // + mask*log2e (fp32 mask, fma)
        #pragma unroll
        for (int kb = 0; kb < 4; ++kb) {
            const float4 mv = *(const float4*)(mrow + kv0 + kb * 16);
            s[kb][0] = fmaf(mv.x, LOG2E, s[kb][0]);
            s[kb][1] = fmaf(mv.y, LOG2E, s[kb][1]);
            s[kb][2] = fmaf(mv.z, LOG2E, s[kb][2]);
            s[kb][3] = fmaf(mv.w, LOG2E, s[kb][3]);
        }

        // online softmax (base-2), rows lane-local
        float mx = fmaxf(fmaxf(s[0][0], s[0][1]), fmaxf(s[0][2], s[0][3]));
        #pragma unroll
        for (int kb = 1; kb < 4; ++kb)
            mx = fmaxf(mx, fmaxf(fmaxf(s[kb][0], s[kb][1]), fmaxf(s[kb][2], s[kb][3])));
        mx = fmaxf(mx, __shfl_xor(mx, 16));
        mx = fmaxf(mx, __shfl_xor(mx, 32));
        const float mn = fmaxf(m2, mx);
        const float al = exp2f(m2 - mn);
        m2 = mn;
        #pragma unroll
        for (int eb = 0; eb < 4; ++eb) o[eb] *= al;
        float rs = 0.f;
        unsigned w0[4], w1[4];
        #pragma unroll
        for (int kb = 0; kb < 4; ++kb) {
            const float p0 = exp2f(s[kb][0] - mn);
            const float p1 = exp2f(s[kb][1] - mn);
            const float p2 = exp2f(s[kb][2] - mn);
            const float p3 = exp2f(s[kb][3] - mn);
            rs += (p0 + p1) + (p2 + p3);
            w0[kb] = pk2(p0, p1);
            w1[kb] = pk2(p2, p3);
        }
        lp = lp * al + rs;
        bf16x8 pb[2];
        #pragma unroll
        for (int kbp = 0; kbp < 2; ++kbp) {
            const uint4 u = {w0[2 * kbp], w1[2 * kbp], w0[2 * kbp + 1], w1[2 * kbp + 1]};
            pb[kbp] = __builtin_bit_cast(bf16x8, u);
        }

        // O^T += V^T P^T  (K=32 MFMA, custom k<->kv bijection; V pre-permuted)
        #pragma unroll
        for (int kbp = 0; kbp < 2; ++kbp)
            #pragma unroll
            for (int eb = 0; eb < 4; ++eb) {
                const bf16x8 va = frag_swz(&Vs[cur][0], eb * 16 + l15, kbp * 4 + quad);
                o[eb] = MFMA16(va, pb[kbp], o[eb]);
            }
    }

    // epilogue: finish row sums, normalize, write O^T, row-norm reduction
    float lf = lp;
    lf += __shfl_xor(lf, 16);
    lf += __shfl_xor(lf, 32);
    const float inv = 1.f / lf;
    float ss = 0.f;
    #pragma unroll
    for (int eb = 0; eb < 4; ++eb) {
        o[eb] *= inv;
        #pragma unroll
        for (int r = 0; r < 4; ++r) ss += o[eb][r] * o[eb][r];
    }
    ss += __shfl_xor(ss, 16);
    ss += __shfl_xor(ss, 32);
    const float tot = sqrtf(ss);

    #pragma unroll
    for (int eb = 0; eb < 4; ++eb) {
        uint2 pk;
        pk.x = pk2(o[eb][0], o[eb][1]);
        pk.y = pk2(o[eb][2], o[eb][3]);
        *(uint2*)&Ob[((long)(b * 2048 + qrow)) * 1024 + h * 64 + eb * 16 + quad * 4] = pk;
    }
    // each row's norm appears in 4 lanes (quads): sum all, divide by 4
    const float wsum = red_add64(tot) * 0.25f;
    if (lane == 0) wred[w] = wsum;
    __syncthreads();
    if (tid == 0)
        atomicAdd(&denomsum[h], wred[0] + wred[1] + wred[2] + wred[3]);
}

// ---------------------------------------------------------------------------
// K4: scale WoT rows (per head) by g_h / (denom_h * H), in place.
// WoT regenerated by transpose_w every call -> in-place is replay-safe.
// grid 1024 x 256
// ---------------------------------------------------------------------------
__global__ __launch_bounds__(256) void scale_w_kernel(
    short* __restrict__ WoT, const float* __restrict__ denomsum,
    const float* __restrict__ gate)
{
    __shared__ float sh[16];
    if (threadIdx.x < 16) {
        const float g  = fminf(fmaxf(gate[threadIdx.x], 0.f), 1.f);
        const float dn = fmaxf(denomsum[threadIdx.x] * (1.f / (float)BT), 1e-5f);
        sh[threadIdx.x] = g / (dn * (float)NUM_HEADS);
    }
    __syncthreads();
    const long i = ((long)blockIdx.x * 256 + threadIdx.x) * 4;
    const float sc = sh[(int)(i >> 16)];
    ushort4 v = *(ushort4*)(WoT + i);
    v.x = (unsigned short)f2bf(bf2f((short)v.x) * sc);
    v.y = (unsigned short)f2bf(bf2f((short)v.y) * sc);
    v.z = (unsigned short)f2bf(bf2f((short)v.z) * sc);
    v.w = (unsigned short)f2bf(bf2f((short)v.w) * sc);
    *(ushort4*)(WoT + i) = v;
}

// ---------------------------------------------------------------------------
// K5: output projection, MFMA, double-buffered single-barrier prefetch over
// the 16 head-chunks (grid 256 blocks = 1 block/CU -> latency must be hidden
// inside the block).  BM=BN=128.
// ---------------------------------------------------------------------------
__global__ __launch_bounds__(256) void oproj_mfma_kernel(
    const short* __restrict__ Ob,    // [4096][1024] raw attention out
    const short* __restrict__ WoT,   // [16][1024][64], pre-scaled by s_h
    const float* __restrict__ bo,    // [16][1024]
    const float* __restrict__ gate,
    float* __restrict__ out)         // [4096][1024]
{
    const int m0 = blockIdx.x * 128;
    const int n0 = blockIdx.y * 128;
    __shared__ short As[2][128 * 64];
    __shared__ short Bs[2][128 * 64];

    const int tid = threadIdx.x, lane = tid & 63, w = tid >> 6;
    const int wm = w & 1, wn = w >> 1;
    const int quad = lane >> 4, l15 = lane & 15;

    auto stage = [&](int h, int buf) {
        #pragma unroll
        for (int t = 0; t < 4; ++t) {
            const int r0 = w * 32 + t * 8;
            const int r  = r0 + (lane >> 3);
            const int cg = (lane & 7) ^ (r & 7);
            gld16(Ob + (long)(m0 + r) * 1024 + h * 64 + cg * 8, &As[buf][r0 * 64]);
            gld16(WoT + (long)h * 65536 + (long)(n0 + r) * 64 + cg * 8, &Bs[buf][r0 * 64]);
        }
    };

    f32x4 acc[4][4] = {};
    stage(0, 0);

    for (int h = 0; h < 16; ++h) {
        const int cur = h & 1;
        __syncthreads();
        if (h < 15) stage(h + 1, cur ^ 1);
        #pragma unroll
        for (int ks = 0; ks < 2; ++ks) {
            bf16x8 af[4];
            #pragma unroll
            for (int ms = 0; ms < 4; ++ms)
                af[ms] = frag_swz(&As[cur][0], wm * 64 + ms * 16 + l15, ks * 4 + quad);
            #pragma unroll
            for (int ns = 0; ns < 4; ++ns) {
                const bf16x8 bfr = frag_swz(&Bs[cur][0], wn * 64 + ns * 16 + l15, ks * 4 + quad);
                #pragma unroll
                for (int ms = 0; ms < 4; ++ms)
                    acc[ms][ns] = MFMA16(af[ms], bfr, acc[ms][ns]);
            }
        }
    }

    // epilogue: bias_eff[n] = sum_h clamp(g_h)*bo[h][n]/16
    float gcl[16];
    #pragma unroll
    for (int hh = 0; hh < 16; ++hh)
        gcl[hh] = fminf(fmaxf(gate[hh], 0.f), 1.f) * (1.f / (float)NUM_HEADS);

    #pragma unroll
    for (int ns = 0; ns < 4; ++ns) {
        const int n = n0 + wn * 64 + ns * 16 + l15;
        float be = 0.f;
        #pragma unroll
        for (int hh = 0; hh < 16; ++hh) be += gcl[hh] * bo[hh * 1024 + n];
        #pragma unroll
        for (int ms = 0; ms < 4; ++ms) {
            const int m = m0 + wm * 64 + ms * 16 + quad * 4;
            #pragma unroll
            for (int r = 0; r < 4; ++r)
                out[(long)(m + r) * 1024 + n] = acc[ms][ns][r] + be;
        }
    }
}

// ---------------------------------------------------------------------------
extern "C" void kernel_launch(void* const* d_in, const int* in_sizes, int n_in,
                              void* d_out, int out_size, void* d_ws, size_t ws_size,
                              hipStream_t stream)
{
    const float* hs   = (const float*)d_in[0];
    const float* mask = (const float*)d_in[1];
    const float* Wq   = (const float*)d_in[2];
    const float* bq   = (const float*)d_in[3];
    const float* Wk   = (const float*)d_in[4];
    const float* bk   = (const float*)d_in[5];
    const float* Wv   = (const float*)d_in[6];
    const float* bv   = (const float*)d_in[7];
    const float* Wo   = (const float*)d_in[8];
    const float* bo   = (const float*)d_in[9];
    const float* gate = (const float*)d_in[10];
    float* out = (float*)d_out;

    char* ws = (char*)d_ws;
    const size_t MB = 1024 * 1024;
    short* hsb   = (short*)(ws);                 // 8 MB  (4096x1024)
    short* Wqt   = (short*)(ws + 8  * MB);       // 2 MB -- Wqt/Wkt/Wvt contiguous = Wt [3072][1024]
    short* Wkt   = (short*)(ws + 10 * MB);       // 2 MB
    short* Wvt   = (short*)(ws + 12 * MB);       // 2 MB
    short* WoT   = (short*)(ws + 14 * MB);       // 2 MB  (16x1024x64)
    short* Qb    = (short*)(ws + 16 * MB);       // 8 MB  [b,h,t,e]
    short* Kb    = (short*)(ws + 24 * MB);       // 8 MB  [b,h,t,e]
    short* Vtb   = (short*)(ws + 32 * MB);       // 8 MB  [b,h,e,t'] (kv-permuted)
    short* Ob    = (short*)(ws + 40 * MB);       // 8 MB  [b,t,h*64+e]
    float* denomsum = (float*)(ws + 48 * MB);    // 16 floats

    (void)hipMemsetAsync(denomsum, 0, NUM_HEADS * sizeof(float), stream);

    cvt_in_kernel<<<4096, 256, 0, stream>>>(hs, hsb);
    transpose_w_kernel<<<dim3(64, 16, 4), 256, 0, stream>>>(
        Wq, Wk, Wv, Wo, Wqt, Wkt, Wvt, WoT);
    qkv_mfma_kernel<<<dim3(32, 24), 256, 0, stream>>>(
        hsb, Wqt, bq, bk, bv, Qb, Kb, Vtb);
    attn_mfma_kernel<<<dim3(32, 16, 2), 256, 0, stream>>>(
        Qb, Kb, Vtb, mask, Ob, denomsum);
    scale_w_kernel<<<1024, 256, 0, stream>>>(WoT, denomsum, gate);
    oproj_mfma_kernel<<<dim3(32, 8), 256, 0, stream>>>(
        Ob, WoT, bo, gate, out);
}